// Round 10
// baseline (218.528 us; speedup 1.0000x reference)
//
#include <hip/hip_runtime.h>

#define NN 4096   // W*H
#define LOG2E 1.4426950408889634f
// layouts in d_ws:
//   Qg  [B][N][8] bf16 : g-projection (row i)
//   Kf  [B][N][8] bf16 : f-projection * log2e (row j)
//   V   [B][C][N] bf16 : h-projection
//   Lsp [B][N] u32     : packed {bf16 hi, bf16 lo} of  -log2(z_j)

typedef unsigned short u16;
typedef __attribute__((ext_vector_type(8))) short bf16x8;
typedef __attribute__((ext_vector_type(4))) float f32x4;

__device__ __forceinline__ u16 f2bf(float f){
  union { float f; unsigned u; } v; v.f = f;
  unsigned r = v.u + 0x7fffu + ((v.u >> 16) & 1u);   // RNE
  return (u16)(r >> 16);
}
__device__ __forceinline__ float bf2f(u16 h){
  union { unsigned u; float f; } v; v.u = ((unsigned)h) << 16;
  return v.f;
}

// ---------------- prep: 1x1 convs ---------------- (r7-verified, unchanged)
__global__ __launch_bounds__(256) void prep_kernel(
    const float* __restrict__ x,
    const float* __restrict__ Wf, const float* __restrict__ bfv,
    const float* __restrict__ Wg, const float* __restrict__ bgv,
    const float* __restrict__ Wh, const float* __restrict__ bhv,
    u16* __restrict__ Qg, u16* __restrict__ Kf, u16* __restrict__ V)
{
  __shared__ float xl[64][68];   // [pixel][channel]
  const int tid = threadIdx.x;
  const int lane = tid & 63, q = tid >> 6;   // q is wave-uniform
  const int b = blockIdx.x >> 6;
  const int i0 = (blockIdx.x & 63) << 6;
  const float* xb = x + ((size_t)b << 18);

  for (int r = 0; r < 16; ++r){
    int c = r * 4 + q;
    xl[lane][c] = xb[((size_t)c << 12) + i0 + lane];
  }
  __syncthreads();

  float xr[64];
#pragma unroll
  for (int c4 = 0; c4 < 16; ++c4){
    f32x4 v = *(const f32x4*)&xl[lane][c4 << 2];
    xr[c4*4+0]=v[0]; xr[c4*4+1]=v[1]; xr[c4*4+2]=v[2]; xr[c4*4+3]=v[3];
  }

  u16* vp = V + ((size_t)b << 18) + i0 + lane;
  for (int ch = 0; ch < 16; ++ch){
    int co = (q << 4) + ch;
    float acc = bhv[co];
    const float* wr = Wh + (co << 6);
#pragma unroll
    for (int c = 0; c < 64; ++c) acc = fmaf(wr[c], xr[c], acc);
    vp[(size_t)co << 12] = f2bf(acc);
  }
  {
    const int row = (b << 12) + i0 + lane;
    float a0 = bfv[2*q], a1 = bfv[2*q+1], c0 = bgv[2*q], c1 = bgv[2*q+1];
    const float* w0 = Wf + ((2*q) << 6); const float* w1 = Wf + ((2*q+1) << 6);
    const float* u0 = Wg + ((2*q) << 6); const float* u1 = Wg + ((2*q+1) << 6);
#pragma unroll
    for (int c = 0; c < 64; ++c){
      float xv = xr[c];
      a0 = fmaf(w0[c], xv, a0); a1 = fmaf(w1[c], xv, a1);
      c0 = fmaf(u0[c], xv, c0); c1 = fmaf(u1[c], xv, c1);
    }
    unsigned pf = f2bf(a0 * LOG2E) | ((unsigned)f2bf(a1 * LOG2E) << 16);
    unsigned pg = f2bf(c0) | ((unsigned)f2bf(c1) << 16);
    *(unsigned*)(Kf + (size_t)row * 8 + 2*q) = pf;
    *(unsigned*)(Qg + (size_t)row * 8 + 2*q) = pg;
  }
}

// ---------------- pass1 ---------------- (r7-verified, unchanged)
__global__ __launch_bounds__(256, 8) void pass1_kernel(
    const u16* __restrict__ Qg, const u16* __restrict__ Kf, unsigned* __restrict__ Lsp)
{
  __shared__ float zp[4][16];
  const int tid = threadIdx.x;
  const int w = tid >> 6, lane = tid & 63;
  const int l15 = lane & 15, g = lane >> 4;
  const int b = blockIdx.x >> 8;
  const int j0 = (blockIdx.x & 255) << 4;

  bf16x8 af = {0,0,0,0,0,0,0,0};
  if (lane < 16) af = *(const bf16x8*)(Kf + ((size_t)((b << 12) + j0 + lane)) * 8);

  const u16* qb = Qg + ((size_t)(b << 12)) * 8;
  float z0=0.f, z1=0.f, z2=0.f, z3=0.f;
  const f32x4 zero4 = {0.f,0.f,0.f,0.f};
  const int ibase = w << 10;
  for (int t = 0; t < 32; ++t){
    const int i = ibase + (t << 5);
    bf16x8 b0 = {0,0,0,0,0,0,0,0}, b1 = {0,0,0,0,0,0,0,0};
    if (lane < 16){
      b0 = *(const bf16x8*)(qb + (size_t)(i + lane) * 8);
      b1 = *(const bf16x8*)(qb + (size_t)(i + 16 + lane) * 8);
    }
    f32x4 s0 = __builtin_amdgcn_mfma_f32_16x16x32_bf16(af, b0, zero4, 0,0,0);
    f32x4 s1 = __builtin_amdgcn_mfma_f32_16x16x32_bf16(af, b1, zero4, 0,0,0);
    z0 += __builtin_amdgcn_exp2f(s0[0]) + __builtin_amdgcn_exp2f(s1[0]);
    z1 += __builtin_amdgcn_exp2f(s0[1]) + __builtin_amdgcn_exp2f(s1[1]);
    z2 += __builtin_amdgcn_exp2f(s0[2]) + __builtin_amdgcn_exp2f(s1[2]);
    z3 += __builtin_amdgcn_exp2f(s0[3]) + __builtin_amdgcn_exp2f(s1[3]);
  }
  float zz[4] = {z0,z1,z2,z3};
#pragma unroll
  for (int r = 0; r < 4; ++r){
#pragma unroll
    for (int off = 1; off < 16; off <<= 1)
      zz[r] += __shfl_xor(zz[r], off, 64);
  }
  if (l15 == 0){
#pragma unroll
    for (int r = 0; r < 4; ++r) zp[w][(g << 2) + r] = zz[r];
  }
  __syncthreads();
  if (tid < 16){
    float zs = zp[0][tid] + zp[1][tid] + zp[2][tid] + zp[3][tid];
    float nL = -__log2f(zs);
    u16 hi = f2bf(nL);
    u16 lo = f2bf(nL - bf2f(hi));
    Lsp[((size_t)b << 12) + j0 + tid] = (unsigned)hi | ((unsigned)lo << 16);
  }
}

// build PV B-operand fragment (r7-verified, unchanged)
__device__ __forceinline__ bf16x8 build_pb(const f32x4 sl, const f32x4 sh, int g, int l15){
  float e0 = __builtin_amdgcn_exp2f(sl[0]), e1 = __builtin_amdgcn_exp2f(sl[1]);
  float e2 = __builtin_amdgcn_exp2f(sl[2]), e3 = __builtin_amdgcn_exp2f(sl[3]);
  float h0 = __builtin_amdgcn_exp2f(sh[0]), h1 = __builtin_amdgcn_exp2f(sh[1]);
  float h2 = __builtin_amdgcn_exp2f(sh[2]), h3 = __builtin_amdgcn_exp2f(sh[3]);
  unsigned P0 = (unsigned)f2bf(e0) | ((unsigned)f2bf(e1) << 16);
  unsigned P1 = (unsigned)f2bf(e2) | ((unsigned)f2bf(e3) << 16);
  unsigned Q0 = (unsigned)f2bf(h0) | ((unsigned)f2bf(h1) << 16);
  unsigned Q1 = (unsigned)f2bf(h2) | ((unsigned)f2bf(h3) << 16);
  const int sA = (((g << 1) & 3) << 4) + l15;
  const int sB = ((((g << 1) + 1) & 3) << 4) + l15;
  int A0 = __shfl((int)P0, sA, 64), A1 = __shfl((int)P1, sA, 64);
  int A2 = __shfl((int)Q0, sA, 64), A3 = __shfl((int)Q1, sA, 64);
  int B0 = __shfl((int)P0, sB, 64), B1 = __shfl((int)P1, sB, 64);
  int B2 = __shfl((int)Q0, sB, 64), B3 = __shfl((int)Q1, sB, 64);
  const bool hi = (g >= 2);
  union { int d[4]; bf16x8 v; } u;
  u.d[0] = hi ? A2 : A0;   // {P[8g+0], P[8g+1]}
  u.d[1] = hi ? A3 : A1;   // {P[8g+2], P[8g+3]}
  u.d[2] = hi ? B2 : B0;   // {P[8g+4], P[8g+5]}
  u.d[3] = hi ? B3 : B1;   // {P[8g+6], P[8g+7]}
  return u.v;
}

// ---------------- pass2: O[c,i] = sum_j 2^{S2[j,i]-log2 z_j} * V[c,j]; out = gamma*O + x --------
// r7 per-wave shape (32 i-rows, 2 subtiles -- the measured-optimal overhead:MFMA ratio),
// but j split 8 ways: 512-thread blocks, 8 waves, 16 iters each. 1024 blocks x 8 waves
// = 8192 waves = 100% chip capacity (vs r7's 4096). Datapath byte-identical to r7.
// XCD swizzle (r8-verified): b = bid&7 -> each XCD's L2 holds one batch's V + Kf.
__global__ __launch_bounds__(512, 8) void pass2_kernel(
    const u16* __restrict__ Qg, const u16* __restrict__ Kf,
    const u16* __restrict__ V, const unsigned* __restrict__ Lsp,
    const float* __restrict__ x, const float* __restrict__ gammap,
    float* __restrict__ out)
{
  __shared__ __align__(16) float Of[4][32][68];   // 34.8 KB, epilogue only
  const int tid = threadIdx.x;
  const int w = tid >> 6, lane = tid & 63;        // w = j-eighth
  const int l15 = lane & 15, g = lane >> 4;
  const int bid = blockIdx.x;
  const int b = bid & 7;                          // per-batch XCD chunking (1024 % 8 == 0)
  const int i0b = (bid >> 3) << 5;                // 32-row i-tile

  const u16* kb = Kf + ((size_t)(b << 12)) * 8;
  const u16* vb = V + ((size_t)b << 18);
  const unsigned* Lb = Lsp + ((size_t)b << 12);

  bf16x8 qf0 = {0,0,0,0,0,0,0,0}, qf1 = {0,0,0,0,0,0,0,0};
  if (lane < 16){
    qf0 = *(const bf16x8*)(Qg + ((size_t)((b << 12) + i0b + lane)) * 8);
    qf1 = *(const bf16x8*)(Qg + ((size_t)((b << 12) + i0b + 16 + lane)) * 8);
  } else if (lane < 32){
    ((unsigned*)&qf0)[0] = 0x3F803F80u;   // k=8,9 partners = 1.0,1.0
    ((unsigned*)&qf1)[0] = 0x3F803F80u;
  }

  f32x4 acc[2][4];
#pragma unroll
  for (int s = 0; s < 2; ++s)
#pragma unroll
    for (int ct = 0; ct < 4; ++ct) acc[s][ct] = (f32x4){0.f,0.f,0.f,0.f};

  const f32x4 zero4 = {0.f,0.f,0.f,0.f};
  const int jbase = w << 9;                        // 512-j range per wave

  for (int t = 0; t < 16; ++t){
    const int j0 = jbase + (t << 5);
    // K rows (+ -log2 z in k=8,9 lanes)
    bf16x8 kk0 = {0,0,0,0,0,0,0,0}, kk1 = {0,0,0,0,0,0,0,0};
    if (lane < 16){
      kk0 = *(const bf16x8*)(kb + (size_t)(j0 + lane) * 8);
      kk1 = *(const bf16x8*)(kb + (size_t)(j0 + 16 + lane) * 8);
    } else if (lane < 32){
      ((unsigned*)&kk0)[0] = Lb[j0 + l15];        // {-Lg_hi, -Lg_lo}
      ((unsigned*)&kk1)[0] = Lb[j0 + 16 + l15];
    }
    // V fragments (A-operand rows c, k=j), shared by both i-subtiles
    bf16x8 vf0 = *(const bf16x8*)(vb + (((size_t)( 0 + l15)) << 12) + j0 + (g << 3));
    bf16x8 vf1 = *(const bf16x8*)(vb + (((size_t)(16 + l15)) << 12) + j0 + (g << 3));
    bf16x8 vf2 = *(const bf16x8*)(vb + (((size_t)(32 + l15)) << 12) + j0 + (g << 3));
    bf16x8 vf3 = *(const bf16x8*)(vb + (((size_t)(48 + l15)) << 12) + j0 + (g << 3));
    // swapped QK^T with -log2(z) folded in
    f32x4 sl0 = __builtin_amdgcn_mfma_f32_16x16x32_bf16(kk0, qf0, zero4, 0,0,0);
    f32x4 sh0 = __builtin_amdgcn_mfma_f32_16x16x32_bf16(kk1, qf0, zero4, 0,0,0);
    f32x4 sl1 = __builtin_amdgcn_mfma_f32_16x16x32_bf16(kk0, qf1, zero4, 0,0,0);
    f32x4 sh1 = __builtin_amdgcn_mfma_f32_16x16x32_bf16(kk1, qf1, zero4, 0,0,0);
    bf16x8 pb0 = build_pb(sl0, sh0, g, l15);
    bf16x8 pb1 = build_pb(sl1, sh1, g, l15);
    // PV: O[c,i] += V x P
    __builtin_amdgcn_s_setprio(1);
    acc[0][0] = __builtin_amdgcn_mfma_f32_16x16x32_bf16(vf0, pb0, acc[0][0], 0,0,0);
    acc[0][1] = __builtin_amdgcn_mfma_f32_16x16x32_bf16(vf1, pb0, acc[0][1], 0,0,0);
    acc[0][2] = __builtin_amdgcn_mfma_f32_16x16x32_bf16(vf2, pb0, acc[0][2], 0,0,0);
    acc[0][3] = __builtin_amdgcn_mfma_f32_16x16x32_bf16(vf3, pb0, acc[0][3], 0,0,0);
    acc[1][0] = __builtin_amdgcn_mfma_f32_16x16x32_bf16(vf0, pb1, acc[1][0], 0,0,0);
    acc[1][1] = __builtin_amdgcn_mfma_f32_16x16x32_bf16(vf1, pb1, acc[1][1], 0,0,0);
    acc[1][2] = __builtin_amdgcn_mfma_f32_16x16x32_bf16(vf2, pb1, acc[1][2], 0,0,0);
    acc[1][3] = __builtin_amdgcn_mfma_f32_16x16x32_bf16(vf3, pb1, acc[1][3], 0,0,0);
    __builtin_amdgcn_s_setprio(0);
  }

  // epilogue: acc[s][ct][r] = O[c = 16ct+4g+r, i = i0b + 16s + l15] (j-eighth partial)
  // tree combine: waves 0-3 write Of[w], waves 4-7 add into Of[w-4], then sum 4 arrays.
  if (w < 4){
#pragma unroll
    for (int s = 0; s < 2; ++s)
#pragma unroll
      for (int ct = 0; ct < 4; ++ct)
        *(f32x4*)&Of[w][(s << 4) + l15][(ct << 4) + (g << 2)] = acc[s][ct];
  }
  __syncthreads();
  if (w >= 4){
#pragma unroll
    for (int s = 0; s < 2; ++s)
#pragma unroll
      for (int ct = 0; ct < 4; ++ct){
        f32x4* p = (f32x4*)&Of[w - 4][(s << 4) + l15][(ct << 4) + (g << 2)];
        *p += acc[s][ct];
      }
  }
  __syncthreads();
  const float gamma = gammap[0];
  const int il = tid & 31, cg = tid >> 5;   // cg in [0,16)
#pragma unroll
  for (int cc = 0; cc < 4; ++cc){
    const int c = (cg << 2) + cc;
    const size_t idx = (((size_t)((b << 6) + c)) << 12) + i0b + il;
    const float o = Of[0][il][c] + Of[1][il][c] + Of[2][il][c] + Of[3][il][c];
    out[idx] = fmaf(gamma, o, x[idx]);
  }
}

extern "C" void kernel_launch(void* const* d_in, const int* in_sizes, int n_in,
                              void* d_out, int out_size, void* d_ws, size_t ws_size,
                              hipStream_t stream)
{
  (void)in_sizes; (void)n_in; (void)out_size; (void)ws_size;
  const float* x   = (const float*)d_in[0];
  const float* Wf  = (const float*)d_in[1];
  const float* bfv = (const float*)d_in[2];
  const float* Wg  = (const float*)d_in[3];
  const float* bgv = (const float*)d_in[4];
  const float* Wh  = (const float*)d_in[5];
  const float* bhv = (const float*)d_in[6];
  const float* gm  = (const float*)d_in[7];
  float* out = (float*)d_out;

  // workspace: Qg 512K | Kf 512K | V 4M | Lsp 128K  (= 5.125 MB)
  char* ws = (char*)d_ws;
  u16*  Qg = (u16*)(ws);
  u16*  Kf = (u16*)(ws + (1u << 19));
  u16*  Vv = (u16*)(ws + (1u << 20));
  unsigned* Lsp = (unsigned*)(ws + (1u << 20) + (1u << 22));

  prep_kernel<<<512, 256, 0, stream>>>(x, Wf, bfv, Wg, bgv, Wh, bhv, Qg, Kf, Vv);
  pass1_kernel<<<2048, 256, 0, stream>>>(Qg, Kf, Lsp);
  pass2_kernel<<<1024, 512, 0, stream>>>(Qg, Kf, Vv, Lsp, x, gm, out);
}

// Round 11
// 118.243 us; speedup vs baseline: 1.8481x; 1.8481x over previous
//
#include <hip/hip_runtime.h>

#define NN 4096   // W*H
#define LOG2E 1.4426950408889634f
// layouts in d_ws:
//   Qg  [B][N][8] bf16 : g-projection (row i)
//   Kf  [B][N][8] bf16 : f-projection * log2e (row j)
//   V   [B][C][N] bf16 : h-projection
//   Lsp [B][N] u32     : packed {bf16 hi, bf16 lo} of  -log2(z_j)

typedef unsigned short u16;
typedef __attribute__((ext_vector_type(8))) short bf16x8;
typedef __attribute__((ext_vector_type(4))) float f32x4;

__device__ __forceinline__ u16 f2bf(float f){
  union { float f; unsigned u; } v; v.f = f;
  unsigned r = v.u + 0x7fffu + ((v.u >> 16) & 1u);   // RNE
  return (u16)(r >> 16);
}
__device__ __forceinline__ float bf2f(u16 h){
  union { unsigned u; float f; } v; v.u = ((unsigned)h) << 16;
  return v.f;
}

// ---------------- prep: 1x1 convs ---------------- (r7-verified, unchanged)
__global__ __launch_bounds__(256) void prep_kernel(
    const float* __restrict__ x,
    const float* __restrict__ Wf, const float* __restrict__ bfv,
    const float* __restrict__ Wg, const float* __restrict__ bgv,
    const float* __restrict__ Wh, const float* __restrict__ bhv,
    u16* __restrict__ Qg, u16* __restrict__ Kf, u16* __restrict__ V)
{
  __shared__ float xl[64][68];   // [pixel][channel]
  const int tid = threadIdx.x;
  const int lane = tid & 63, q = tid >> 6;   // q is wave-uniform
  const int b = blockIdx.x >> 6;
  const int i0 = (blockIdx.x & 63) << 6;
  const float* xb = x + ((size_t)b << 18);

  for (int r = 0; r < 16; ++r){
    int c = r * 4 + q;
    xl[lane][c] = xb[((size_t)c << 12) + i0 + lane];
  }
  __syncthreads();

  float xr[64];
#pragma unroll
  for (int c4 = 0; c4 < 16; ++c4){
    f32x4 v = *(const f32x4*)&xl[lane][c4 << 2];
    xr[c4*4+0]=v[0]; xr[c4*4+1]=v[1]; xr[c4*4+2]=v[2]; xr[c4*4+3]=v[3];
  }

  u16* vp = V + ((size_t)b << 18) + i0 + lane;
  for (int ch = 0; ch < 16; ++ch){
    int co = (q << 4) + ch;
    float acc = bhv[co];
    const float* wr = Wh + (co << 6);
#pragma unroll
    for (int c = 0; c < 64; ++c) acc = fmaf(wr[c], xr[c], acc);
    vp[(size_t)co << 12] = f2bf(acc);
  }
  {
    const int row = (b << 12) + i0 + lane;
    float a0 = bfv[2*q], a1 = bfv[2*q+1], c0 = bgv[2*q], c1 = bgv[2*q+1];
    const float* w0 = Wf + ((2*q) << 6); const float* w1 = Wf + ((2*q+1) << 6);
    const float* u0 = Wg + ((2*q) << 6); const float* u1 = Wg + ((2*q+1) << 6);
#pragma unroll
    for (int c = 0; c < 64; ++c){
      float xv = xr[c];
      a0 = fmaf(w0[c], xv, a0); a1 = fmaf(w1[c], xv, a1);
      c0 = fmaf(u0[c], xv, c0); c1 = fmaf(u1[c], xv, c1);
    }
    unsigned pf = f2bf(a0 * LOG2E) | ((unsigned)f2bf(a1 * LOG2E) << 16);
    unsigned pg = f2bf(c0) | ((unsigned)f2bf(c1) << 16);
    *(unsigned*)(Kf + (size_t)row * 8 + 2*q) = pf;
    *(unsigned*)(Qg + (size_t)row * 8 + 2*q) = pg;
  }
}

// ---------------- pass1 ---------------- (r7-verified, unchanged)
__global__ __launch_bounds__(256, 8) void pass1_kernel(
    const u16* __restrict__ Qg, const u16* __restrict__ Kf, unsigned* __restrict__ Lsp)
{
  __shared__ float zp[4][16];
  const int tid = threadIdx.x;
  const int w = tid >> 6, lane = tid & 63;
  const int l15 = lane & 15, g = lane >> 4;
  const int b = blockIdx.x >> 8;
  const int j0 = (blockIdx.x & 255) << 4;

  bf16x8 af = {0,0,0,0,0,0,0,0};
  if (lane < 16) af = *(const bf16x8*)(Kf + ((size_t)((b << 12) + j0 + lane)) * 8);

  const u16* qb = Qg + ((size_t)(b << 12)) * 8;
  float z0=0.f, z1=0.f, z2=0.f, z3=0.f;
  const f32x4 zero4 = {0.f,0.f,0.f,0.f};
  const int ibase = w << 10;
  for (int t = 0; t < 32; ++t){
    const int i = ibase + (t << 5);
    bf16x8 b0 = {0,0,0,0,0,0,0,0}, b1 = {0,0,0,0,0,0,0,0};
    if (lane < 16){
      b0 = *(const bf16x8*)(qb + (size_t)(i + lane) * 8);
      b1 = *(const bf16x8*)(qb + (size_t)(i + 16 + lane) * 8);
    }
    f32x4 s0 = __builtin_amdgcn_mfma_f32_16x16x32_bf16(af, b0, zero4, 0,0,0);
    f32x4 s1 = __builtin_amdgcn_mfma_f32_16x16x32_bf16(af, b1, zero4, 0,0,0);
    z0 += __builtin_amdgcn_exp2f(s0[0]) + __builtin_amdgcn_exp2f(s1[0]);
    z1 += __builtin_amdgcn_exp2f(s0[1]) + __builtin_amdgcn_exp2f(s1[1]);
    z2 += __builtin_amdgcn_exp2f(s0[2]) + __builtin_amdgcn_exp2f(s1[2]);
    z3 += __builtin_amdgcn_exp2f(s0[3]) + __builtin_amdgcn_exp2f(s1[3]);
  }
  float zz[4] = {z0,z1,z2,z3};
#pragma unroll
  for (int r = 0; r < 4; ++r){
#pragma unroll
    for (int off = 1; off < 16; off <<= 1)
      zz[r] += __shfl_xor(zz[r], off, 64);
  }
  if (l15 == 0){
#pragma unroll
    for (int r = 0; r < 4; ++r) zp[w][(g << 2) + r] = zz[r];
  }
  __syncthreads();
  if (tid < 16){
    float zs = zp[0][tid] + zp[1][tid] + zp[2][tid] + zp[3][tid];
    float nL = -__log2f(zs);
    u16 hi = f2bf(nL);
    u16 lo = f2bf(nL - bf2f(hi));
    Lsp[((size_t)b << 12) + j0 + tid] = (unsigned)hi | ((unsigned)lo << 16);
  }
}

// build PV B-operand fragment (r7-verified, unchanged)
__device__ __forceinline__ bf16x8 build_pb(const f32x4 sl, const f32x4 sh, int g, int l15){
  float e0 = __builtin_amdgcn_exp2f(sl[0]), e1 = __builtin_amdgcn_exp2f(sl[1]);
  float e2 = __builtin_amdgcn_exp2f(sl[2]), e3 = __builtin_amdgcn_exp2f(sl[3]);
  float h0 = __builtin_amdgcn_exp2f(sh[0]), h1 = __builtin_amdgcn_exp2f(sh[1]);
  float h2 = __builtin_amdgcn_exp2f(sh[2]), h3 = __builtin_amdgcn_exp2f(sh[3]);
  unsigned P0 = (unsigned)f2bf(e0) | ((unsigned)f2bf(e1) << 16);
  unsigned P1 = (unsigned)f2bf(e2) | ((unsigned)f2bf(e3) << 16);
  unsigned Q0 = (unsigned)f2bf(h0) | ((unsigned)f2bf(h1) << 16);
  unsigned Q1 = (unsigned)f2bf(h2) | ((unsigned)f2bf(h3) << 16);
  const int sA = (((g << 1) & 3) << 4) + l15;
  const int sB = ((((g << 1) + 1) & 3) << 4) + l15;
  int A0 = __shfl((int)P0, sA, 64), A1 = __shfl((int)P1, sA, 64);
  int A2 = __shfl((int)Q0, sA, 64), A3 = __shfl((int)Q1, sA, 64);
  int B0 = __shfl((int)P0, sB, 64), B1 = __shfl((int)P1, sB, 64);
  int B2 = __shfl((int)Q0, sB, 64), B3 = __shfl((int)Q1, sB, 64);
  const bool hi = (g >= 2);
  union { int d[4]; bf16x8 v; } u;
  u.d[0] = hi ? A2 : A0;   // {P[8g+0], P[8g+1]}
  u.d[1] = hi ? A3 : A1;   // {P[8g+2], P[8g+3]}
  u.d[2] = hi ? B2 : B0;   // {P[8g+4], P[8g+5]}
  u.d[3] = hi ? B3 : B1;   // {P[8g+6], P[8g+7]}
  return u.v;
}

// ---------------- pass2: O[c,i] = sum_j 2^{S2[j,i]-log2 z_j} * V[c,j]; out = gamma*O + x --------
// r7 structure (verified best: 1024 blocks x 4 waves, 32 i-rows/wave, j-quarters) plus:
//   (1) K/L register prefetch one iteration ahead -- removes exposed L2 latency from the
//       QK->exp->bpermute->PV chain without reordering compute (r8's failure was the
//       build_P placement, not the prefetch);
//   (2) XCD swizzle b=bid&7 (r8-verified FETCH 23.3->11.4 MB): each XCD's L2 holds one
//       batch's V (512 KB) + Kf -- better L2 hit rate on the K/V loads.
__global__ __launch_bounds__(256, 4) void pass2_kernel(
    const u16* __restrict__ Qg, const u16* __restrict__ Kf,
    const u16* __restrict__ V, const unsigned* __restrict__ Lsp,
    const float* __restrict__ x, const float* __restrict__ gammap,
    float* __restrict__ out)
{
  __shared__ __align__(16) float Of[2][32][68];   // 17.4 KB, epilogue only
  const int tid = threadIdx.x;
  const int w = tid >> 6, lane = tid & 63;        // w = jq
  const int l15 = lane & 15, g = lane >> 4;
  const int bid = blockIdx.x;
  const int b = bid & 7;                          // per-batch XCD chunking (1024 % 8 == 0)
  const int i0b = (bid >> 3) << 5;                // 32-row i-tile

  const u16* kb = Kf + ((size_t)(b << 12)) * 8;
  const u16* vb = V + ((size_t)b << 18);
  const unsigned* Lb = Lsp + ((size_t)b << 12);

  bf16x8 qf0 = {0,0,0,0,0,0,0,0}, qf1 = {0,0,0,0,0,0,0,0};
  if (lane < 16){
    qf0 = *(const bf16x8*)(Qg + ((size_t)((b << 12) + i0b + lane)) * 8);
    qf1 = *(const bf16x8*)(Qg + ((size_t)((b << 12) + i0b + 16 + lane)) * 8);
  } else if (lane < 32){
    ((unsigned*)&qf0)[0] = 0x3F803F80u;   // k=8,9 partners = 1.0,1.0
    ((unsigned*)&qf1)[0] = 0x3F803F80u;
  }

  f32x4 acc[2][4];
#pragma unroll
  for (int s = 0; s < 2; ++s)
#pragma unroll
    for (int ct = 0; ct < 4; ++ct) acc[s][ct] = (f32x4){0.f,0.f,0.f,0.f};

  const f32x4 zero4 = {0.f,0.f,0.f,0.f};
  const int jbase = w << 10;

  auto load_k = [&](int j0, bf16x8& kk0, bf16x8& kk1){
    kk0 = (bf16x8){0,0,0,0,0,0,0,0}; kk1 = (bf16x8){0,0,0,0,0,0,0,0};
    if (lane < 16){
      kk0 = *(const bf16x8*)(kb + (size_t)(j0 + lane) * 8);
      kk1 = *(const bf16x8*)(kb + (size_t)(j0 + 16 + lane) * 8);
    } else if (lane < 32){
      ((unsigned*)&kk0)[0] = Lb[j0 + l15];        // k=8,9: {-Lg_hi, -Lg_lo}
      ((unsigned*)&kk1)[0] = Lb[j0 + 16 + l15];
    }
  };

  bf16x8 kc0, kc1;
  load_k(jbase, kc0, kc1);                        // K/L(0)

  for (int t = 0; t < 32; ++t){
    const int j0 = jbase + (t << 5);
    // prefetch K/L(t+1): loads issue non-blocking here, consumed next iteration
    bf16x8 kn0, kn1;
    if (t < 31) load_k(j0 + 32, kn0, kn1);
    // V fragments (A-operand rows c, k=j), shared by both i-subtiles
    bf16x8 vf0 = *(const bf16x8*)(vb + (((size_t)( 0 + l15)) << 12) + j0 + (g << 3));
    bf16x8 vf1 = *(const bf16x8*)(vb + (((size_t)(16 + l15)) << 12) + j0 + (g << 3));
    bf16x8 vf2 = *(const bf16x8*)(vb + (((size_t)(32 + l15)) << 12) + j0 + (g << 3));
    bf16x8 vf3 = *(const bf16x8*)(vb + (((size_t)(48 + l15)) << 12) + j0 + (g << 3));
    // swapped QK^T with -log2(z) folded in (kc ready since last iteration)
    f32x4 sl0 = __builtin_amdgcn_mfma_f32_16x16x32_bf16(kc0, qf0, zero4, 0,0,0);
    f32x4 sh0 = __builtin_amdgcn_mfma_f32_16x16x32_bf16(kc1, qf0, zero4, 0,0,0);
    f32x4 sl1 = __builtin_amdgcn_mfma_f32_16x16x32_bf16(kc0, qf1, zero4, 0,0,0);
    f32x4 sh1 = __builtin_amdgcn_mfma_f32_16x16x32_bf16(kc1, qf1, zero4, 0,0,0);
    bf16x8 pb0 = build_pb(sl0, sh0, g, l15);
    bf16x8 pb1 = build_pb(sl1, sh1, g, l15);
    // PV: O[c,i] += V x P
    __builtin_amdgcn_s_setprio(1);
    acc[0][0] = __builtin_amdgcn_mfma_f32_16x16x32_bf16(vf0, pb0, acc[0][0], 0,0,0);
    acc[0][1] = __builtin_amdgcn_mfma_f32_16x16x32_bf16(vf1, pb0, acc[0][1], 0,0,0);
    acc[0][2] = __builtin_amdgcn_mfma_f32_16x16x32_bf16(vf2, pb0, acc[0][2], 0,0,0);
    acc[0][3] = __builtin_amdgcn_mfma_f32_16x16x32_bf16(vf3, pb0, acc[0][3], 0,0,0);
    acc[1][0] = __builtin_amdgcn_mfma_f32_16x16x32_bf16(vf0, pb1, acc[1][0], 0,0,0);
    acc[1][1] = __builtin_amdgcn_mfma_f32_16x16x32_bf16(vf1, pb1, acc[1][1], 0,0,0);
    acc[1][2] = __builtin_amdgcn_mfma_f32_16x16x32_bf16(vf2, pb1, acc[1][2], 0,0,0);
    acc[1][3] = __builtin_amdgcn_mfma_f32_16x16x32_bf16(vf3, pb1, acc[1][3], 0,0,0);
    __builtin_amdgcn_s_setprio(0);
    kc0 = kn0; kc1 = kn1;
  }

  // epilogue (r7-verified, unchanged): two-phase partial combine through LDS
  if (w < 2){
#pragma unroll
    for (int s = 0; s < 2; ++s)
#pragma unroll
      for (int ct = 0; ct < 4; ++ct)
        *(f32x4*)&Of[w][(s << 4) + l15][(ct << 4) + (g << 2)] = acc[s][ct];
  }
  __syncthreads();
  if (w >= 2){
#pragma unroll
    for (int s = 0; s < 2; ++s)
#pragma unroll
      for (int ct = 0; ct < 4; ++ct){
        f32x4* p = (f32x4*)&Of[w - 2][(s << 4) + l15][(ct << 4) + (g << 2)];
        *p += acc[s][ct];
      }
  }
  __syncthreads();
  const float gamma = gammap[0];
  const int il = tid & 31, cg = tid >> 5;   // cg in [0,8)
#pragma unroll
  for (int cc = 0; cc < 8; ++cc){
    const int c = (cg << 3) + cc;
    const size_t idx = (((size_t)((b << 6) + c)) << 12) + i0b + il;
    const float o = Of[0][il][c] + Of[1][il][c];
    out[idx] = fmaf(gamma, o, x[idx]);
  }
}

extern "C" void kernel_launch(void* const* d_in, const int* in_sizes, int n_in,
                              void* d_out, int out_size, void* d_ws, size_t ws_size,
                              hipStream_t stream)
{
  (void)in_sizes; (void)n_in; (void)out_size; (void)ws_size;
  const float* x   = (const float*)d_in[0];
  const float* Wf  = (const float*)d_in[1];
  const float* bfv = (const float*)d_in[2];
  const float* Wg  = (const float*)d_in[3];
  const float* bgv = (const float*)d_in[4];
  const float* Wh  = (const float*)d_in[5];
  const float* bhv = (const float*)d_in[6];
  const float* gm  = (const float*)d_in[7];
  float* out = (float*)d_out;

  // workspace: Qg 512K | Kf 512K | V 4M | Lsp 128K  (= 5.125 MB)
  char* ws = (char*)d_ws;
  u16*  Qg = (u16*)(ws);
  u16*  Kf = (u16*)(ws + (1u << 19));
  u16*  Vv = (u16*)(ws + (1u << 20));
  unsigned* Lsp = (unsigned*)(ws + (1u << 20) + (1u << 22));

  prep_kernel<<<512, 256, 0, stream>>>(x, Wf, bfv, Wg, bgv, Wh, bhv, Qg, Kf, Vv);
  pass1_kernel<<<2048, 256, 0, stream>>>(Qg, Kf, Lsp);
  pass2_kernel<<<1024, 256, 0, stream>>>(Qg, Kf, Vv, Lsp, x, gm, out);
}

// Round 13
// 117.347 us; speedup vs baseline: 1.8622x; 1.0076x over previous
//
#include <hip/hip_runtime.h>

#define NN 4096   // W*H
#define LOG2E 1.4426950408889634f
// layouts in d_ws (r11-verified):
//   Qg  [B][N][8] bf16 : g-projection (row i)
//   Kf  [B][N][8] bf16 : f-projection * log2e (row j), natural order
//   V   [B][C][N] bf16 : h-projection
//   Lsp [B][N] u32     : packed {bf16 hi, bf16 lo} of  -log2(z_j)

typedef unsigned short u16;
typedef __attribute__((ext_vector_type(8))) short bf16x8;
typedef __attribute__((ext_vector_type(4))) float f32x4;

__device__ __forceinline__ u16 f2bf(float f){
  union { float f; unsigned u; } v; v.f = f;
  unsigned r = v.u + 0x7fffu + ((v.u >> 16) & 1u);   // RNE
  return (u16)(r >> 16);
}
__device__ __forceinline__ float bf2f(u16 h){
  union { unsigned u; float f; } v; v.u = ((unsigned)h) << 16;
  return v.f;
}

// ---------------- prep: 1x1 convs ----------------
// r7 datapath, 8 waves/block (2x concurrency for the FLOP-bound kernel):
// wave-uniform slice q8 = tid>>6: 8 h-channels + 1 f + 1 g per thread.
__global__ __launch_bounds__(512, 4) void prep_kernel(
    const float* __restrict__ x,
    const float* __restrict__ Wf, const float* __restrict__ bfv,
    const float* __restrict__ Wg, const float* __restrict__ bgv,
    const float* __restrict__ Wh, const float* __restrict__ bhv,
    u16* __restrict__ Qg, u16* __restrict__ Kf, u16* __restrict__ V)
{
  __shared__ float xl[64][68];   // [pixel][channel]
  const int tid = threadIdx.x;
  const int lane = tid & 63, q8 = tid >> 6;   // q8 in [0,8), wave-uniform
  const int b = blockIdx.x >> 6;
  const int i0 = (blockIdx.x & 63) << 6;
  const float* xb = x + ((size_t)b << 18);

  // stage x[b][c][i0..i0+63] -> xl[p][c] (coalesced over lane)
  for (int r = 0; r < 8; ++r){
    int c = (r << 3) + q8;
    xl[lane][c] = xb[((size_t)c << 12) + i0 + lane];
  }
  __syncthreads();

  float xr[64];
#pragma unroll
  for (int c4 = 0; c4 < 16; ++c4){
    f32x4 v = *(const f32x4*)&xl[lane][c4 << 2];
    xr[c4*4+0]=v[0]; xr[c4*4+1]=v[1]; xr[c4*4+2]=v[2]; xr[c4*4+3]=v[3];
  }

  // h-projection: 8 channels per thread (wave-uniform weight rows)
  u16* vp = V + ((size_t)b << 18) + i0 + lane;
#pragma unroll
  for (int ch = 0; ch < 8; ++ch){
    int co = (q8 << 3) + ch;
    float acc = bhv[co];
    const float* wr = Wh + (co << 6);
#pragma unroll
    for (int c = 0; c < 64; ++c) acc = fmaf(wr[c], xr[c], acc);
    vp[(size_t)co << 12] = f2bf(acc);
  }
  // f (scaled by log2e) and g: one output each per thread (slot q8)
  {
    const int row = (b << 12) + i0 + lane;
    float a0 = bfv[q8], c0 = bgv[q8];
    const float* w0 = Wf + (q8 << 6);
    const float* u0 = Wg + (q8 << 6);
#pragma unroll
    for (int c = 0; c < 64; ++c){
      float xv = xr[c];
      a0 = fmaf(w0[c], xv, a0);
      c0 = fmaf(u0[c], xv, c0);
    }
    Kf[(size_t)row * 8 + q8] = f2bf(a0 * LOG2E);
    Qg[(size_t)row * 8 + q8] = f2bf(c0);
  }
}

// ---------------- pass1: Lsp_j = split(-log2 z_j), z_j = sum_i 2^{S2[j,i]} ----------------
// 32-row j-tile per block (2 A-fragments share each Q-fragment load -- halves the
// per-iteration fixed load cost), 4 waves split i 4-way. z-order per row identical to r11.
__global__ __launch_bounds__(256, 4) void pass1_kernel(
    const u16* __restrict__ Qg, const u16* __restrict__ Kf, unsigned* __restrict__ Lsp)
{
  __shared__ float zp[4][32];
  const int tid = threadIdx.x;
  const int w = tid >> 6, lane = tid & 63;
  const int l15 = lane & 15, g = lane >> 4;
  const int b = blockIdx.x >> 7;
  const int j0 = (blockIdx.x & 127) << 5;

  bf16x8 af0 = {0,0,0,0,0,0,0,0}, af1 = {0,0,0,0,0,0,0,0};
  if (lane < 16){
    af0 = *(const bf16x8*)(Kf + ((size_t)((b << 12) + j0 + lane)) * 8);
    af1 = *(const bf16x8*)(Kf + ((size_t)((b << 12) + j0 + 16 + lane)) * 8);
  }

  const u16* qb = Qg + ((size_t)(b << 12)) * 8;
  float z[8];
#pragma unroll
  for (int r = 0; r < 8; ++r) z[r] = 0.f;
  const f32x4 zero4 = {0.f,0.f,0.f,0.f};
  const int ibase = w << 10;
  for (int t = 0; t < 32; ++t){
    const int i = ibase + (t << 5);
    bf16x8 b0 = {0,0,0,0,0,0,0,0}, b1 = {0,0,0,0,0,0,0,0};
    if (lane < 16){
      b0 = *(const bf16x8*)(qb + (size_t)(i + lane) * 8);
      b1 = *(const bf16x8*)(qb + (size_t)(i + 16 + lane) * 8);
    }
    f32x4 s00 = __builtin_amdgcn_mfma_f32_16x16x32_bf16(af0, b0, zero4, 0,0,0);
    f32x4 s01 = __builtin_amdgcn_mfma_f32_16x16x32_bf16(af0, b1, zero4, 0,0,0);
    f32x4 s10 = __builtin_amdgcn_mfma_f32_16x16x32_bf16(af1, b0, zero4, 0,0,0);
    f32x4 s11 = __builtin_amdgcn_mfma_f32_16x16x32_bf16(af1, b1, zero4, 0,0,0);
#pragma unroll
    for (int r = 0; r < 4; ++r){
      z[r]     += __builtin_amdgcn_exp2f(s00[r]) + __builtin_amdgcn_exp2f(s01[r]);
      z[4 + r] += __builtin_amdgcn_exp2f(s10[r]) + __builtin_amdgcn_exp2f(s11[r]);
    }
  }
#pragma unroll
  for (int r = 0; r < 8; ++r){
#pragma unroll
    for (int off = 1; off < 16; off <<= 1)
      z[r] += __shfl_xor(z[r], off, 64);
  }
  if (l15 == 0){
#pragma unroll
    for (int r = 0; r < 4; ++r){
      zp[w][(g << 2) + r]      = z[r];
      zp[w][16 + (g << 2) + r] = z[4 + r];
    }
  }
  __syncthreads();
  if (tid < 32){
    float zs = zp[0][tid] + zp[1][tid] + zp[2][tid] + zp[3][tid];
    float nL = -__log2f(zs);
    u16 hi = f2bf(nL);
    u16 lo = f2bf(nL - bf2f(hi));
    Lsp[((size_t)b << 12) + j0 + tid] = (unsigned)hi | ((unsigned)lo << 16);
  }
}

// build PV B-operand fragment (r7/r11-verified, unchanged)
__device__ __forceinline__ bf16x8 build_pb(const f32x4 sl, const f32x4 sh, int g, int l15){
  float e0 = __builtin_amdgcn_exp2f(sl[0]), e1 = __builtin_amdgcn_exp2f(sl[1]);
  float e2 = __builtin_amdgcn_exp2f(sl[2]), e3 = __builtin_amdgcn_exp2f(sl[3]);
  float h0 = __builtin_amdgcn_exp2f(sh[0]), h1 = __builtin_amdgcn_exp2f(sh[1]);
  float h2 = __builtin_amdgcn_exp2f(sh[2]), h3 = __builtin_amdgcn_exp2f(sh[3]);
  unsigned P0 = (unsigned)f2bf(e0) | ((unsigned)f2bf(e1) << 16);
  unsigned P1 = (unsigned)f2bf(e2) | ((unsigned)f2bf(e3) << 16);
  unsigned Q0 = (unsigned)f2bf(h0) | ((unsigned)f2bf(h1) << 16);
  unsigned Q1 = (unsigned)f2bf(h2) | ((unsigned)f2bf(h3) << 16);
  const int sA = (((g << 1) & 3) << 4) + l15;
  const int sB = ((((g << 1) + 1) & 3) << 4) + l15;
  int A0 = __shfl((int)P0, sA, 64), A1 = __shfl((int)P1, sA, 64);
  int A2 = __shfl((int)Q0, sA, 64), A3 = __shfl((int)Q1, sA, 64);
  int B0 = __shfl((int)P0, sB, 64), B1 = __shfl((int)P1, sB, 64);
  int B2 = __shfl((int)Q0, sB, 64), B3 = __shfl((int)Q1, sB, 64);
  const bool hi = (g >= 2);
  union { int d[4]; bf16x8 v; } u;
  u.d[0] = hi ? A2 : A0;   // {P[8g+0], P[8g+1]}
  u.d[1] = hi ? A3 : A1;   // {P[8g+2], P[8g+3]}
  u.d[2] = hi ? B2 : B0;   // {P[8g+4], P[8g+5]}
  u.d[3] = hi ? B3 : B1;   // {P[8g+6], P[8g+7]}
  return u.v;
}

// ---------------- pass2 ---------------- (r11-verified kernel, byte-identical)
__global__ __launch_bounds__(256, 4) void pass2_kernel(
    const u16* __restrict__ Qg, const u16* __restrict__ Kf,
    const u16* __restrict__ V, const unsigned* __restrict__ Lsp,
    const float* __restrict__ x, const float* __restrict__ gammap,
    float* __restrict__ out)
{
  __shared__ __align__(16) float Of[2][32][68];   // 17.4 KB, epilogue only
  const int tid = threadIdx.x;
  const int w = tid >> 6, lane = tid & 63;        // w = jq
  const int l15 = lane & 15, g = lane >> 4;
  const int bid = blockIdx.x;
  const int b = bid & 7;                          // per-batch XCD chunking (1024 % 8 == 0)
  const int i0b = (bid >> 3) << 5;                // 32-row i-tile

  const u16* kb = Kf + ((size_t)(b << 12)) * 8;
  const u16* vb = V + ((size_t)b << 18);
  const unsigned* Lb = Lsp + ((size_t)b << 12);

  bf16x8 qf0 = {0,0,0,0,0,0,0,0}, qf1 = {0,0,0,0,0,0,0,0};
  if (lane < 16){
    qf0 = *(const bf16x8*)(Qg + ((size_t)((b << 12) + i0b + lane)) * 8);
    qf1 = *(const bf16x8*)(Qg + ((size_t)((b << 12) + i0b + 16 + lane)) * 8);
  } else if (lane < 32){
    ((unsigned*)&qf0)[0] = 0x3F803F80u;   // k=8,9 partners = 1.0,1.0
    ((unsigned*)&qf1)[0] = 0x3F803F80u;
  }

  f32x4 acc[2][4];
#pragma unroll
  for (int s = 0; s < 2; ++s)
#pragma unroll
    for (int ct = 0; ct < 4; ++ct) acc[s][ct] = (f32x4){0.f,0.f,0.f,0.f};

  const f32x4 zero4 = {0.f,0.f,0.f,0.f};
  const int jbase = w << 10;

  auto load_k = [&](int j0, bf16x8& kk0, bf16x8& kk1){
    kk0 = (bf16x8){0,0,0,0,0,0,0,0}; kk1 = (bf16x8){0,0,0,0,0,0,0,0};
    if (lane < 16){
      kk0 = *(const bf16x8*)(kb + (size_t)(j0 + lane) * 8);
      kk1 = *(const bf16x8*)(kb + (size_t)(j0 + 16 + lane) * 8);
    } else if (lane < 32){
      ((unsigned*)&kk0)[0] = Lb[j0 + l15];        // k=8,9: {-Lg_hi, -Lg_lo}
      ((unsigned*)&kk1)[0] = Lb[j0 + 16 + l15];
    }
  };

  bf16x8 kc0, kc1;
  load_k(jbase, kc0, kc1);                        // K/L(0)

  for (int t = 0; t < 32; ++t){
    const int j0 = jbase + (t << 5);
    // prefetch K/L(t+1): non-blocking issue, consumed next iteration
    bf16x8 kn0 = {0,0,0,0,0,0,0,0}, kn1 = {0,0,0,0,0,0,0,0};
    if (t < 31) load_k(j0 + 32, kn0, kn1);
    // V fragments (A-operand rows c, k=j), shared by both i-subtiles
    bf16x8 vf0 = *(const bf16x8*)(vb + (((size_t)( 0 + l15)) << 12) + j0 + (g << 3));
    bf16x8 vf1 = *(const bf16x8*)(vb + (((size_t)(16 + l15)) << 12) + j0 + (g << 3));
    bf16x8 vf2 = *(const bf16x8*)(vb + (((size_t)(32 + l15)) << 12) + j0 + (g << 3));
    bf16x8 vf3 = *(const bf16x8*)(vb + (((size_t)(48 + l15)) << 12) + j0 + (g << 3));
    // swapped QK^T with -log2(z) folded in (kc ready since last iteration)
    f32x4 sl0 = __builtin_amdgcn_mfma_f32_16x16x32_bf16(kc0, qf0, zero4, 0,0,0);
    f32x4 sh0 = __builtin_amdgcn_mfma_f32_16x16x32_bf16(kc1, qf0, zero4, 0,0,0);
    f32x4 sl1 = __builtin_amdgcn_mfma_f32_16x16x32_bf16(kc0, qf1, zero4, 0,0,0);
    f32x4 sh1 = __builtin_amdgcn_mfma_f32_16x16x32_bf16(kc1, qf1, zero4, 0,0,0);
    bf16x8 pb0 = build_pb(sl0, sh0, g, l15);
    bf16x8 pb1 = build_pb(sl1, sh1, g, l15);
    // PV: O[c,i] += V x P
    __builtin_amdgcn_s_setprio(1);
    acc[0][0] = __builtin_amdgcn_mfma_f32_16x16x32_bf16(vf0, pb0, acc[0][0], 0,0,0);
    acc[0][1] = __builtin_amdgcn_mfma_f32_16x16x32_bf16(vf1, pb0, acc[0][1], 0,0,0);
    acc[0][2] = __builtin_amdgcn_mfma_f32_16x16x32_bf16(vf2, pb0, acc[0][2], 0,0,0);
    acc[0][3] = __builtin_amdgcn_mfma_f32_16x16x32_bf16(vf3, pb0, acc[0][3], 0,0,0);
    acc[1][0] = __builtin_amdgcn_mfma_f32_16x16x32_bf16(vf0, pb1, acc[1][0], 0,0,0);
    acc[1][1] = __builtin_amdgcn_mfma_f32_16x16x32_bf16(vf1, pb1, acc[1][1], 0,0,0);
    acc[1][2] = __builtin_amdgcn_mfma_f32_16x16x32_bf16(vf2, pb1, acc[1][2], 0,0,0);
    acc[1][3] = __builtin_amdgcn_mfma_f32_16x16x32_bf16(vf3, pb1, acc[1][3], 0,0,0);
    __builtin_amdgcn_s_setprio(0);
    kc0 = kn0; kc1 = kn1;
  }

  // epilogue (r7/r11-verified, unchanged): two-phase partial combine through LDS
  if (w < 2){
#pragma unroll
    for (int s = 0; s < 2; ++s)
#pragma unroll
      for (int ct = 0; ct < 4; ++ct)
        *(f32x4*)&Of[w][(s << 4) + l15][(ct << 4) + (g << 2)] = acc[s][ct];
  }
  __syncthreads();
  if (w >= 2){
#pragma unroll
    for (int s = 0; s < 2; ++s)
#pragma unroll
      for (int ct = 0; ct < 4; ++ct){
        f32x4* p = (f32x4*)&Of[w - 2][(s << 4) + l15][(ct << 4) + (g << 2)];
        *p += acc[s][ct];
      }
  }
  __syncthreads();
  const float gamma = gammap[0];
  const int il = tid & 31, cg = tid >> 5;   // cg in [0,8)
#pragma unroll
  for (int cc = 0; cc < 8; ++cc){
    const int c = (cg << 3) + cc;
    const size_t idx = (((size_t)((b << 6) + c)) << 12) + i0b + il;
    const float o = Of[0][il][c] + Of[1][il][c];
    out[idx] = fmaf(gamma, o, x[idx]);
  }
}

extern "C" void kernel_launch(void* const* d_in, const int* in_sizes, int n_in,
                              void* d_out, int out_size, void* d_ws, size_t ws_size,
                              hipStream_t stream)
{
  (void)in_sizes; (void)n_in; (void)out_size; (void)ws_size;
  const float* x   = (const float*)d_in[0];
  const float* Wf  = (const float*)d_in[1];
  const float* bfv = (const float*)d_in[2];
  const float* Wg  = (const float*)d_in[3];
  const float* bgv = (const float*)d_in[4];
  const float* Wh  = (const float*)d_in[5];
  const float* bhv = (const float*)d_in[6];
  const float* gm  = (const float*)d_in[7];
  float* out = (float*)d_out;

  // workspace: Qg 512K | Kf 512K | V 4M | Lsp 128K  (= 5.125 MB)
  char* ws = (char*)d_ws;
  u16*  Qg = (u16*)(ws);
  u16*  Kf = (u16*)(ws + (1u << 19));
  u16*  Vv = (u16*)(ws + (1u << 20));
  unsigned* Lsp = (unsigned*)(ws + (1u << 20) + (1u << 22));

  prep_kernel<<<512, 512, 0, stream>>>(x, Wf, bfv, Wg, bgv, Wh, bhv, Qg, Kf, Vv);
  pass1_kernel<<<1024, 256, 0, stream>>>(Qg, Kf, Lsp);
  pass2_kernel<<<1024, 256, 0, stream>>>(Qg, Kf, Vv, Lsp, x, gm, out);
}

// Round 14
// 116.424 us; speedup vs baseline: 1.8770x; 1.0079x over previous
//
#include <hip/hip_runtime.h>

#define NN 4096   // W*H
#define LOG2E 1.4426950408889634f
// layouts in d_ws (r11-verified):
//   Qg  [B][N][8] bf16 : g-projection (row i)
//   Kf  [B][N][8] bf16 : f-projection * log2e (row j), natural order
//   V   [B][C][N] bf16 : h-projection
//   Lsp [B][N] u32     : packed {bf16 hi, bf16 lo} of  -log2(z_j)

typedef unsigned short u16;
typedef __attribute__((ext_vector_type(8))) short bf16x8;
typedef __attribute__((ext_vector_type(4))) float f32x4;

__device__ __forceinline__ u16 f2bf(float f){
  union { float f; unsigned u; } v; v.f = f;
  unsigned r = v.u + 0x7fffu + ((v.u >> 16) & 1u);   // RNE
  return (u16)(r >> 16);
}
__device__ __forceinline__ float bf2f(u16 h){
  union { unsigned u; float f; } v; v.u = ((unsigned)h) << 16;
  return v.f;
}

// ---------------- prep: 1x1 convs ---------------- (r13-verified, unchanged)
__global__ __launch_bounds__(512, 4) void prep_kernel(
    const float* __restrict__ x,
    const float* __restrict__ Wf, const float* __restrict__ bfv,
    const float* __restrict__ Wg, const float* __restrict__ bgv,
    const float* __restrict__ Wh, const float* __restrict__ bhv,
    u16* __restrict__ Qg, u16* __restrict__ Kf, u16* __restrict__ V)
{
  __shared__ float xl[64][68];   // [pixel][channel]
  const int tid = threadIdx.x;
  const int lane = tid & 63, q8 = tid >> 6;   // q8 in [0,8), wave-uniform
  const int b = blockIdx.x >> 6;
  const int i0 = (blockIdx.x & 63) << 6;
  const float* xb = x + ((size_t)b << 18);

  for (int r = 0; r < 8; ++r){
    int c = (r << 3) + q8;
    xl[lane][c] = xb[((size_t)c << 12) + i0 + lane];
  }
  __syncthreads();

  float xr[64];
#pragma unroll
  for (int c4 = 0; c4 < 16; ++c4){
    f32x4 v = *(const f32x4*)&xl[lane][c4 << 2];
    xr[c4*4+0]=v[0]; xr[c4*4+1]=v[1]; xr[c4*4+2]=v[2]; xr[c4*4+3]=v[3];
  }

  u16* vp = V + ((size_t)b << 18) + i0 + lane;
#pragma unroll
  for (int ch = 0; ch < 8; ++ch){
    int co = (q8 << 3) + ch;
    float acc = bhv[co];
    const float* wr = Wh + (co << 6);
#pragma unroll
    for (int c = 0; c < 64; ++c) acc = fmaf(wr[c], xr[c], acc);
    vp[(size_t)co << 12] = f2bf(acc);
  }
  {
    const int row = (b << 12) + i0 + lane;
    float a0 = bfv[q8], c0 = bgv[q8];
    const float* w0 = Wf + (q8 << 6);
    const float* u0 = Wg + (q8 << 6);
#pragma unroll
    for (int c = 0; c < 64; ++c){
      float xv = xr[c];
      a0 = fmaf(w0[c], xv, a0);
      c0 = fmaf(u0[c], xv, c0);
    }
    Kf[(size_t)row * 8 + q8] = f2bf(a0 * LOG2E);
    Qg[(size_t)row * 8 + q8] = f2bf(c0);
  }
}

// ---------------- pass1 ---------------- (r13-verified, unchanged)
__global__ __launch_bounds__(256, 4) void pass1_kernel(
    const u16* __restrict__ Qg, const u16* __restrict__ Kf, unsigned* __restrict__ Lsp)
{
  __shared__ float zp[4][32];
  const int tid = threadIdx.x;
  const int w = tid >> 6, lane = tid & 63;
  const int l15 = lane & 15, g = lane >> 4;
  const int b = blockIdx.x >> 7;
  const int j0 = (blockIdx.x & 127) << 5;

  bf16x8 af0 = {0,0,0,0,0,0,0,0}, af1 = {0,0,0,0,0,0,0,0};
  if (lane < 16){
    af0 = *(const bf16x8*)(Kf + ((size_t)((b << 12) + j0 + lane)) * 8);
    af1 = *(const bf16x8*)(Kf + ((size_t)((b << 12) + j0 + 16 + lane)) * 8);
  }

  const u16* qb = Qg + ((size_t)(b << 12)) * 8;
  float z[8];
#pragma unroll
  for (int r = 0; r < 8; ++r) z[r] = 0.f;
  const f32x4 zero4 = {0.f,0.f,0.f,0.f};
  const int ibase = w << 10;
  for (int t = 0; t < 32; ++t){
    const int i = ibase + (t << 5);
    bf16x8 b0 = {0,0,0,0,0,0,0,0}, b1 = {0,0,0,0,0,0,0,0};
    if (lane < 16){
      b0 = *(const bf16x8*)(qb + (size_t)(i + lane) * 8);
      b1 = *(const bf16x8*)(qb + (size_t)(i + 16 + lane) * 8);
    }
    f32x4 s00 = __builtin_amdgcn_mfma_f32_16x16x32_bf16(af0, b0, zero4, 0,0,0);
    f32x4 s01 = __builtin_amdgcn_mfma_f32_16x16x32_bf16(af0, b1, zero4, 0,0,0);
    f32x4 s10 = __builtin_amdgcn_mfma_f32_16x16x32_bf16(af1, b0, zero4, 0,0,0);
    f32x4 s11 = __builtin_amdgcn_mfma_f32_16x16x32_bf16(af1, b1, zero4, 0,0,0);
#pragma unroll
    for (int r = 0; r < 4; ++r){
      z[r]     += __builtin_amdgcn_exp2f(s00[r]) + __builtin_amdgcn_exp2f(s01[r]);
      z[4 + r] += __builtin_amdgcn_exp2f(s10[r]) + __builtin_amdgcn_exp2f(s11[r]);
    }
  }
#pragma unroll
  for (int r = 0; r < 8; ++r){
#pragma unroll
    for (int off = 1; off < 16; off <<= 1)
      z[r] += __shfl_xor(z[r], off, 64);
  }
  if (l15 == 0){
#pragma unroll
    for (int r = 0; r < 4; ++r){
      zp[w][(g << 2) + r]      = z[r];
      zp[w][16 + (g << 2) + r] = z[4 + r];
    }
  }
  __syncthreads();
  if (tid < 32){
    float zs = zp[0][tid] + zp[1][tid] + zp[2][tid] + zp[3][tid];
    float nL = -__log2f(zs);
    u16 hi = f2bf(nL);
    u16 lo = f2bf(nL - bf2f(hi));
    Lsp[((size_t)b << 12) + j0 + tid] = (unsigned)hi | ((unsigned)lo << 16);
  }
}

// build PV B-operand fragment (r7/r11-verified, unchanged)
__device__ __forceinline__ bf16x8 build_pb(const f32x4 sl, const f32x4 sh, int g, int l15){
  float e0 = __builtin_amdgcn_exp2f(sl[0]), e1 = __builtin_amdgcn_exp2f(sl[1]);
  float e2 = __builtin_amdgcn_exp2f(sl[2]), e3 = __builtin_amdgcn_exp2f(sl[3]);
  float h0 = __builtin_amdgcn_exp2f(sh[0]), h1 = __builtin_amdgcn_exp2f(sh[1]);
  float h2 = __builtin_amdgcn_exp2f(sh[2]), h3 = __builtin_amdgcn_exp2f(sh[3]);
  unsigned P0 = (unsigned)f2bf(e0) | ((unsigned)f2bf(e1) << 16);
  unsigned P1 = (unsigned)f2bf(e2) | ((unsigned)f2bf(e3) << 16);
  unsigned Q0 = (unsigned)f2bf(h0) | ((unsigned)f2bf(h1) << 16);
  unsigned Q1 = (unsigned)f2bf(h2) | ((unsigned)f2bf(h3) << 16);
  const int sA = (((g << 1) & 3) << 4) + l15;
  const int sB = ((((g << 1) + 1) & 3) << 4) + l15;
  int A0 = __shfl((int)P0, sA, 64), A1 = __shfl((int)P1, sA, 64);
  int A2 = __shfl((int)Q0, sA, 64), A3 = __shfl((int)Q1, sA, 64);
  int B0 = __shfl((int)P0, sB, 64), B1 = __shfl((int)P1, sB, 64);
  int B2 = __shfl((int)Q0, sB, 64), B3 = __shfl((int)Q1, sB, 64);
  const bool hi = (g >= 2);
  union { int d[4]; bf16x8 v; } u;
  u.d[0] = hi ? A2 : A0;   // {P[8g+0], P[8g+1]}
  u.d[1] = hi ? A3 : A1;   // {P[8g+2], P[8g+3]}
  u.d[2] = hi ? B2 : B0;   // {P[8g+4], P[8g+5]}
  u.d[3] = hi ? B3 : B1;   // {P[8g+6], P[8g+7]}
  return u.v;
}

// ---------------- pass2: O[c,i] = sum_j 2^{S2[j,i]-log2 z_j} * V[c,j]; out = gamma*O + x --------
// r11 per-wave datapath BYTE-IDENTICAL (32 i-rows, 2 subtiles, K/L prefetch, XCD swizzle),
// aggregated into 8-wave blocks: wave w owns j in [512w, 512w+512) (16 iters).
// 1024 blocks x 8 waves = 8192 waves = 32 waves/CU (r10's geometry, WITHOUT its
// (512,8) register cap -- (512,4) caps at 128, datapath needs ~52).
__global__ __launch_bounds__(512, 4) void pass2_kernel(
    const u16* __restrict__ Qg, const u16* __restrict__ Kf,
    const u16* __restrict__ V, const unsigned* __restrict__ Lsp,
    const float* __restrict__ x, const float* __restrict__ gammap,
    float* __restrict__ out)
{
  __shared__ __align__(16) float Of[4][32][68];   // 34.8 KB, epilogue only
  const int tid = threadIdx.x;
  const int w = tid >> 6, lane = tid & 63;        // w = j-eighth
  const int l15 = lane & 15, g = lane >> 4;
  const int bid = blockIdx.x;
  const int b = bid & 7;                          // per-batch XCD chunking (1024 % 8 == 0)
  const int i0b = (bid >> 3) << 5;                // 32-row i-tile

  const u16* kb = Kf + ((size_t)(b << 12)) * 8;
  const u16* vb = V + ((size_t)b << 18);
  const unsigned* Lb = Lsp + ((size_t)b << 12);

  bf16x8 qf0 = {0,0,0,0,0,0,0,0}, qf1 = {0,0,0,0,0,0,0,0};
  if (lane < 16){
    qf0 = *(const bf16x8*)(Qg + ((size_t)((b << 12) + i0b + lane)) * 8);
    qf1 = *(const bf16x8*)(Qg + ((size_t)((b << 12) + i0b + 16 + lane)) * 8);
  } else if (lane < 32){
    ((unsigned*)&qf0)[0] = 0x3F803F80u;   // k=8,9 partners = 1.0,1.0
    ((unsigned*)&qf1)[0] = 0x3F803F80u;
  }

  f32x4 acc[2][4];
#pragma unroll
  for (int s = 0; s < 2; ++s)
#pragma unroll
    for (int ct = 0; ct < 4; ++ct) acc[s][ct] = (f32x4){0.f,0.f,0.f,0.f};

  const f32x4 zero4 = {0.f,0.f,0.f,0.f};
  const int jbase = w << 9;                        // 512-j range per wave

  auto load_k = [&](int j0, bf16x8& kk0, bf16x8& kk1){
    kk0 = (bf16x8){0,0,0,0,0,0,0,0}; kk1 = (bf16x8){0,0,0,0,0,0,0,0};
    if (lane < 16){
      kk0 = *(const bf16x8*)(kb + (size_t)(j0 + lane) * 8);
      kk1 = *(const bf16x8*)(kb + (size_t)(j0 + 16 + lane) * 8);
    } else if (lane < 32){
      ((unsigned*)&kk0)[0] = Lb[j0 + l15];        // k=8,9: {-Lg_hi, -Lg_lo}
      ((unsigned*)&kk1)[0] = Lb[j0 + 16 + l15];
    }
  };

  bf16x8 kc0, kc1;
  load_k(jbase, kc0, kc1);                        // K/L(0)

  for (int t = 0; t < 16; ++t){
    const int j0 = jbase + (t << 5);
    // prefetch K/L(t+1): non-blocking issue, consumed next iteration
    bf16x8 kn0 = {0,0,0,0,0,0,0,0}, kn1 = {0,0,0,0,0,0,0,0};
    if (t < 15) load_k(j0 + 32, kn0, kn1);
    // V fragments (A-operand rows c, k=j), shared by both i-subtiles
    bf16x8 vf0 = *(const bf16x8*)(vb + (((size_t)( 0 + l15)) << 12) + j0 + (g << 3));
    bf16x8 vf1 = *(const bf16x8*)(vb + (((size_t)(16 + l15)) << 12) + j0 + (g << 3));
    bf16x8 vf2 = *(const bf16x8*)(vb + (((size_t)(32 + l15)) << 12) + j0 + (g << 3));
    bf16x8 vf3 = *(const bf16x8*)(vb + (((size_t)(48 + l15)) << 12) + j0 + (g << 3));
    // swapped QK^T with -log2(z) folded in (kc ready since last iteration)
    f32x4 sl0 = __builtin_amdgcn_mfma_f32_16x16x32_bf16(kc0, qf0, zero4, 0,0,0);
    f32x4 sh0 = __builtin_amdgcn_mfma_f32_16x16x32_bf16(kc1, qf0, zero4, 0,0,0);
    f32x4 sl1 = __builtin_amdgcn_mfma_f32_16x16x32_bf16(kc0, qf1, zero4, 0,0,0);
    f32x4 sh1 = __builtin_amdgcn_mfma_f32_16x16x32_bf16(kc1, qf1, zero4, 0,0,0);
    bf16x8 pb0 = build_pb(sl0, sh0, g, l15);
    bf16x8 pb1 = build_pb(sl1, sh1, g, l15);
    // PV: O[c,i] += V x P
    __builtin_amdgcn_s_setprio(1);
    acc[0][0] = __builtin_amdgcn_mfma_f32_16x16x32_bf16(vf0, pb0, acc[0][0], 0,0,0);
    acc[0][1] = __builtin_amdgcn_mfma_f32_16x16x32_bf16(vf1, pb0, acc[0][1], 0,0,0);
    acc[0][2] = __builtin_amdgcn_mfma_f32_16x16x32_bf16(vf2, pb0, acc[0][2], 0,0,0);
    acc[0][3] = __builtin_amdgcn_mfma_f32_16x16x32_bf16(vf3, pb0, acc[0][3], 0,0,0);
    acc[1][0] = __builtin_amdgcn_mfma_f32_16x16x32_bf16(vf0, pb1, acc[1][0], 0,0,0);
    acc[1][1] = __builtin_amdgcn_mfma_f32_16x16x32_bf16(vf1, pb1, acc[1][1], 0,0,0);
    acc[1][2] = __builtin_amdgcn_mfma_f32_16x16x32_bf16(vf2, pb1, acc[1][2], 0,0,0);
    acc[1][3] = __builtin_amdgcn_mfma_f32_16x16x32_bf16(vf3, pb1, acc[1][3], 0,0,0);
    __builtin_amdgcn_s_setprio(0);
    kc0 = kn0; kc1 = kn1;
  }

  // epilogue: acc[s][ct][r] = O[c = 16ct+4g+r, i = i0b + 16s + l15] (j-eighth partial)
  // tree combine: waves 0-3 write Of[w]; waves 4-7 add into Of[w-4]; final sum of 4.
  if (w < 4){
#pragma unroll
    for (int s = 0; s < 2; ++s)
#pragma unroll
      for (int ct = 0; ct < 4; ++ct)
        *(f32x4*)&Of[w][(s << 4) + l15][(ct << 4) + (g << 2)] = acc[s][ct];
  }
  __syncthreads();
  if (w >= 4){
#pragma unroll
    for (int s = 0; s < 2; ++s)
#pragma unroll
      for (int ct = 0; ct < 4; ++ct){
        f32x4* p = (f32x4*)&Of[w - 4][(s << 4) + l15][(ct << 4) + (g << 2)];
        *p += acc[s][ct];
      }
  }
  __syncthreads();
  const float gamma = gammap[0];
  const int il = tid & 31, cg = tid >> 5;   // cg in [0,16)
#pragma unroll
  for (int cc = 0; cc < 4; ++cc){
    const int c = (cg << 2) + cc;
    const size_t idx = (((size_t)((b << 6) + c)) << 12) + i0b + il;
    const float o = Of[0][il][c] + Of[1][il][c] + Of[2][il][c] + Of[3][il][c];
    out[idx] = fmaf(gamma, o, x[idx]);
  }
}

extern "C" void kernel_launch(void* const* d_in, const int* in_sizes, int n_in,
                              void* d_out, int out_size, void* d_ws, size_t ws_size,
                              hipStream_t stream)
{
  (void)in_sizes; (void)n_in; (void)out_size; (void)ws_size;
  const float* x   = (const float*)d_in[0];
  const float* Wf  = (const float*)d_in[1];
  const float* bfv = (const float*)d_in[2];
  const float* Wg  = (const float*)d_in[3];
  const float* bgv = (const float*)d_in[4];
  const float* Wh  = (const float*)d_in[5];
  const float* bhv = (const float*)d_in[6];
  const float* gm  = (const float*)d_in[7];
  float* out = (float*)d_out;

  // workspace: Qg 512K | Kf 512K | V 4M | Lsp 128K  (= 5.125 MB)
  char* ws = (char*)d_ws;
  u16*  Qg = (u16*)(ws);
  u16*  Kf = (u16*)(ws + (1u << 19));
  u16*  Vv = (u16*)(ws + (1u << 20));
  unsigned* Lsp = (unsigned*)(ws + (1u << 20) + (1u << 22));

  prep_kernel<<<512, 512, 0, stream>>>(x, Wf, bfv, Wg, bgv, Wh, bhv, Qg, Kf, Vv);
  pass1_kernel<<<1024, 256, 0, stream>>>(Qg, Kf, Lsp);
  pass2_kernel<<<1024, 512, 0, stream>>>(Qg, Kf, Vv, Lsp, x, gm, out);
}

// Round 15
// 115.296 us; speedup vs baseline: 1.8954x; 1.0098x over previous
//
#include <hip/hip_runtime.h>

#define NN 4096   // W*H
#define LOG2E 1.4426950408889634f
// layouts in d_ws:
//   Qg  [B][N][8] bf16 : g-projection (row i), natural order
//   Kf  [B][N][8] bf16 : f-projection * log2e (row j), natural order  (r11-verified)
//   V   [B][C][N] bf16 : h-projection, columns PERMUTED within each 32-group:
//                        actual column jl stored at q(jl) = jl<16 ? 8*(jl>>2)+(jl&3)
//                                                         : 8*((jl-16)>>2)+4+((jl-16)&3)
//                        so pass2's natural 16B vf loads deliver A[c,k]=V[c,j0+jmap(k)]
//   Lsp [B][N] u32     : packed {bf16 hi, bf16 lo} of -log2(z_j), natural order

typedef unsigned short u16;
typedef __attribute__((ext_vector_type(8))) short bf16x8;
typedef __attribute__((ext_vector_type(4))) float f32x4;

__device__ __forceinline__ u16 f2bf(float f){
  union { float f; unsigned u; } v; v.f = f;
  unsigned r = v.u + 0x7fffu + ((v.u >> 16) & 1u);   // RNE
  return (u16)(r >> 16);
}
__device__ __forceinline__ float bf2f(u16 h){
  union { unsigned u; float f; } v; v.u = ((unsigned)h) << 16;
  return v.f;
}

// ---------------- prep: 1x1 convs ---------------- (r13-verified; ONLY the V store
// column index changes: within-32 permutation q(jl))
__global__ __launch_bounds__(512, 4) void prep_kernel(
    const float* __restrict__ x,
    const float* __restrict__ Wf, const float* __restrict__ bfv,
    const float* __restrict__ Wg, const float* __restrict__ bgv,
    const float* __restrict__ Wh, const float* __restrict__ bhv,
    u16* __restrict__ Qg, u16* __restrict__ Kf, u16* __restrict__ V)
{
  __shared__ float xl[64][68];   // [pixel][channel]
  const int tid = threadIdx.x;
  const int lane = tid & 63, q8 = tid >> 6;   // q8 in [0,8), wave-uniform
  const int b = blockIdx.x >> 6;
  const int i0 = (blockIdx.x & 63) << 6;
  const float* xb = x + ((size_t)b << 18);

  for (int r = 0; r < 8; ++r){
    int c = (r << 3) + q8;
    xl[lane][c] = xb[((size_t)c << 12) + i0 + lane];
  }
  __syncthreads();

  float xr[64];
#pragma unroll
  for (int c4 = 0; c4 < 16; ++c4){
    f32x4 v = *(const f32x4*)&xl[lane][c4 << 2];
    xr[c4*4+0]=v[0]; xr[c4*4+1]=v[1]; xr[c4*4+2]=v[2]; xr[c4*4+3]=v[3];
  }

  // h-projection: 8 channels per thread; store column at permuted position q(jl)
  const int i = i0 + lane;
  const int jl = i & 31;
  const int qp = (jl < 16) ? (((jl >> 2) << 3) | (jl & 3))
                           : ((((jl - 16) >> 2) << 3) | (4 + ((jl - 16) & 3)));
  u16* vp = V + ((size_t)b << 18) + (size_t)(i & ~31) + qp;
#pragma unroll
  for (int ch = 0; ch < 8; ++ch){
    int co = (q8 << 3) + ch;
    float acc = bhv[co];
    const float* wr = Wh + (co << 6);
#pragma unroll
    for (int c = 0; c < 64; ++c) acc = fmaf(wr[c], xr[c], acc);
    vp[(size_t)co << 12] = f2bf(acc);
  }
  // f (scaled by log2e) and g: natural row order (r13-verified)
  {
    const int row = (b << 12) + i;
    float a0 = bfv[q8], c0 = bgv[q8];
    const float* w0 = Wf + (q8 << 6);
    const float* u0 = Wg + (q8 << 6);
#pragma unroll
    for (int c = 0; c < 64; ++c){
      float xv = xr[c];
      a0 = fmaf(w0[c], xv, a0);
      c0 = fmaf(u0[c], xv, c0);
    }
    Kf[(size_t)row * 8 + q8] = f2bf(a0 * LOG2E);
    Qg[(size_t)row * 8 + q8] = f2bf(c0);
  }
}

// ---------------- pass1 ---------------- (r13-verified, byte-identical; does not read V)
__global__ __launch_bounds__(256, 4) void pass1_kernel(
    const u16* __restrict__ Qg, const u16* __restrict__ Kf, unsigned* __restrict__ Lsp)
{
  __shared__ float zp[4][32];
  const int tid = threadIdx.x;
  const int w = tid >> 6, lane = tid & 63;
  const int l15 = lane & 15, g = lane >> 4;
  const int b = blockIdx.x >> 7;
  const int j0 = (blockIdx.x & 127) << 5;

  bf16x8 af0 = {0,0,0,0,0,0,0,0}, af1 = {0,0,0,0,0,0,0,0};
  if (lane < 16){
    af0 = *(const bf16x8*)(Kf + ((size_t)((b << 12) + j0 + lane)) * 8);
    af1 = *(const bf16x8*)(Kf + ((size_t)((b << 12) + j0 + 16 + lane)) * 8);
  }

  const u16* qb = Qg + ((size_t)(b << 12)) * 8;
  float z[8];
#pragma unroll
  for (int r = 0; r < 8; ++r) z[r] = 0.f;
  const f32x4 zero4 = {0.f,0.f,0.f,0.f};
  const int ibase = w << 10;
  for (int t = 0; t < 32; ++t){
    const int i = ibase + (t << 5);
    bf16x8 b0 = {0,0,0,0,0,0,0,0}, b1 = {0,0,0,0,0,0,0,0};
    if (lane < 16){
      b0 = *(const bf16x8*)(qb + (size_t)(i + lane) * 8);
      b1 = *(const bf16x8*)(qb + (size_t)(i + 16 + lane) * 8);
    }
    f32x4 s00 = __builtin_amdgcn_mfma_f32_16x16x32_bf16(af0, b0, zero4, 0,0,0);
    f32x4 s01 = __builtin_amdgcn_mfma_f32_16x16x32_bf16(af0, b1, zero4, 0,0,0);
    f32x4 s10 = __builtin_amdgcn_mfma_f32_16x16x32_bf16(af1, b0, zero4, 0,0,0);
    f32x4 s11 = __builtin_amdgcn_mfma_f32_16x16x32_bf16(af1, b1, zero4, 0,0,0);
#pragma unroll
    for (int r = 0; r < 4; ++r){
      z[r]     += __builtin_amdgcn_exp2f(s00[r]) + __builtin_amdgcn_exp2f(s01[r]);
      z[4 + r] += __builtin_amdgcn_exp2f(s10[r]) + __builtin_amdgcn_exp2f(s11[r]);
    }
  }
#pragma unroll
  for (int r = 0; r < 8; ++r){
#pragma unroll
    for (int off = 1; off < 16; off <<= 1)
      z[r] += __shfl_xor(z[r], off, 64);
  }
  if (l15 == 0){
#pragma unroll
    for (int r = 0; r < 4; ++r){
      zp[w][(g << 2) + r]      = z[r];
      zp[w][16 + (g << 2) + r] = z[4 + r];
    }
  }
  __syncthreads();
  if (tid < 32){
    float zs = zp[0][tid] + zp[1][tid] + zp[2][tid] + zp[3][tid];
    float nL = -__log2f(zs);
    u16 hi = f2bf(nL);
    u16 lo = f2bf(nL - bf2f(hi));
    Lsp[((size_t)b << 12) + j0 + tid] = (unsigned)hi | ((unsigned)lo << 16);
  }
}

// zero-shuffle P pack: lane g's own QK outputs, in register order, ARE B-slots 8g..8g+7
// (B[k] holds P[j0+jmap(k)]; V's permuted storage makes A[c,k]=V[c,j0+jmap(k)])
__device__ __forceinline__ bf16x8 pack_pb(const f32x4 sl, const f32x4 sh){
  union { unsigned d[4]; bf16x8 v; } u;
  u.d[0] = (unsigned)f2bf(__builtin_amdgcn_exp2f(sl[0])) | ((unsigned)f2bf(__builtin_amdgcn_exp2f(sl[1])) << 16);
  u.d[1] = (unsigned)f2bf(__builtin_amdgcn_exp2f(sl[2])) | ((unsigned)f2bf(__builtin_amdgcn_exp2f(sl[3])) << 16);
  u.d[2] = (unsigned)f2bf(__builtin_amdgcn_exp2f(sh[0])) | ((unsigned)f2bf(__builtin_amdgcn_exp2f(sh[1])) << 16);
  u.d[3] = (unsigned)f2bf(__builtin_amdgcn_exp2f(sh[2])) | ((unsigned)f2bf(__builtin_amdgcn_exp2f(sh[3])) << 16);
  return u.v;
}

// ---------------- pass2 ---------------- (r14-verified geometry & datapath; ONLY change:
// build_pb (16 bpermute + 8 select) -> pack_pb (pure register packing))
__global__ __launch_bounds__(512, 4) void pass2_kernel(
    const u16* __restrict__ Qg, const u16* __restrict__ Kf,
    const u16* __restrict__ V, const unsigned* __restrict__ Lsp,
    const float* __restrict__ x, const float* __restrict__ gammap,
    float* __restrict__ out)
{
  __shared__ __align__(16) float Of[4][32][68];   // 34.8 KB, epilogue only
  const int tid = threadIdx.x;
  const int w = tid >> 6, lane = tid & 63;        // w = j-eighth
  const int l15 = lane & 15, g = lane >> 4;
  const int bid = blockIdx.x;
  const int b = bid & 7;                          // per-batch XCD chunking (1024 % 8 == 0)
  const int i0b = (bid >> 3) << 5;                // 32-row i-tile

  const u16* kb = Kf + ((size_t)(b << 12)) * 8;
  const u16* vb = V + ((size_t)b << 18);
  const unsigned* Lb = Lsp + ((size_t)b << 12);

  bf16x8 qf0 = {0,0,0,0,0,0,0,0}, qf1 = {0,0,0,0,0,0,0,0};
  if (lane < 16){
    qf0 = *(const bf16x8*)(Qg + ((size_t)((b << 12) + i0b + lane)) * 8);
    qf1 = *(const bf16x8*)(Qg + ((size_t)((b << 12) + i0b + 16 + lane)) * 8);
  } else if (lane < 32){
    ((unsigned*)&qf0)[0] = 0x3F803F80u;   // k=8,9 partners = 1.0,1.0
    ((unsigned*)&qf1)[0] = 0x3F803F80u;
  }

  f32x4 acc[2][4];
#pragma unroll
  for (int s = 0; s < 2; ++s)
#pragma unroll
    for (int ct = 0; ct < 4; ++ct) acc[s][ct] = (f32x4){0.f,0.f,0.f,0.f};

  const f32x4 zero4 = {0.f,0.f,0.f,0.f};
  const int jbase = w << 9;                        // 512-j range per wave

  auto load_k = [&](int j0, bf16x8& kk0, bf16x8& kk1){
    kk0 = (bf16x8){0,0,0,0,0,0,0,0}; kk1 = (bf16x8){0,0,0,0,0,0,0,0};
    if (lane < 16){
      kk0 = *(const bf16x8*)(kb + (size_t)(j0 + lane) * 8);
      kk1 = *(const bf16x8*)(kb + (size_t)(j0 + 16 + lane) * 8);
    } else if (lane < 32){
      ((unsigned*)&kk0)[0] = Lb[j0 + l15];        // k=8,9: {-Lg_hi, -Lg_lo}
      ((unsigned*)&kk1)[0] = Lb[j0 + 16 + l15];
    }
  };

  bf16x8 kc0, kc1;
  load_k(jbase, kc0, kc1);                        // K/L(0)

  for (int t = 0; t < 16; ++t){
    const int j0 = jbase + (t << 5);
    // prefetch K/L(t+1): non-blocking issue, consumed next iteration
    bf16x8 kn0 = {0,0,0,0,0,0,0,0}, kn1 = {0,0,0,0,0,0,0,0};
    if (t < 15) load_k(j0 + 32, kn0, kn1);
    // V fragments (A-operand rows c, k-slots from permuted storage), natural addresses
    bf16x8 vf0 = *(const bf16x8*)(vb + (((size_t)( 0 + l15)) << 12) + j0 + (g << 3));
    bf16x8 vf1 = *(const bf16x8*)(vb + (((size_t)(16 + l15)) << 12) + j0 + (g << 3));
    bf16x8 vf2 = *(const bf16x8*)(vb + (((size_t)(32 + l15)) << 12) + j0 + (g << 3));
    bf16x8 vf3 = *(const bf16x8*)(vb + (((size_t)(48 + l15)) << 12) + j0 + (g << 3));
    // swapped QK^T with -log2(z) folded in (kc ready since last iteration)
    f32x4 sl0 = __builtin_amdgcn_mfma_f32_16x16x32_bf16(kc0, qf0, zero4, 0,0,0);
    f32x4 sh0 = __builtin_amdgcn_mfma_f32_16x16x32_bf16(kc1, qf0, zero4, 0,0,0);
    f32x4 sl1 = __builtin_amdgcn_mfma_f32_16x16x32_bf16(kc0, qf1, zero4, 0,0,0);
    f32x4 sh1 = __builtin_amdgcn_mfma_f32_16x16x32_bf16(kc1, qf1, zero4, 0,0,0);
    bf16x8 pb0 = pack_pb(sl0, sh0);
    bf16x8 pb1 = pack_pb(sl1, sh1);
    // PV: O[c,i] += V x P
    __builtin_amdgcn_s_setprio(1);
    acc[0][0] = __builtin_amdgcn_mfma_f32_16x16x32_bf16(vf0, pb0, acc[0][0], 0,0,0);
    acc[0][1] = __builtin_amdgcn_mfma_f32_16x16x32_bf16(vf1, pb0, acc[0][1], 0,0,0);
    acc[0][2] = __builtin_amdgcn_mfma_f32_16x16x32_bf16(vf2, pb0, acc[0][2], 0,0,0);
    acc[0][3] = __builtin_amdgcn_mfma_f32_16x16x32_bf16(vf3, pb0, acc[0][3], 0,0,0);
    acc[1][0] = __builtin_amdgcn_mfma_f32_16x16x32_bf16(vf0, pb1, acc[1][0], 0,0,0);
    acc[1][1] = __builtin_amdgcn_mfma_f32_16x16x32_bf16(vf1, pb1, acc[1][1], 0,0,0);
    acc[1][2] = __builtin_amdgcn_mfma_f32_16x16x32_bf16(vf2, pb1, acc[1][2], 0,0,0);
    acc[1][3] = __builtin_amdgcn_mfma_f32_16x16x32_bf16(vf3, pb1, acc[1][3], 0,0,0);
    __builtin_amdgcn_s_setprio(0);
    kc0 = kn0; kc1 = kn1;
  }

  // epilogue (r14-verified, unchanged): tree combine of 8 j-partials
  if (w < 4){
#pragma unroll
    for (int s = 0; s < 2; ++s)
#pragma unroll
      for (int ct = 0; ct < 4; ++ct)
        *(f32x4*)&Of[w][(s << 4) + l15][(ct << 4) + (g << 2)] = acc[s][ct];
  }
  __syncthreads();
  if (w >= 4){
#pragma unroll
    for (int s = 0; s < 2; ++s)
#pragma unroll
      for (int ct = 0; ct < 4; ++ct){
        f32x4* p = (f32x4*)&Of[w - 4][(s << 4) + l15][(ct << 4) + (g << 2)];
        *p += acc[s][ct];
      }
  }
  __syncthreads();
  const float gamma = gammap[0];
  const int il = tid & 31, cg = tid >> 5;   // cg in [0,16)
#pragma unroll
  for (int cc = 0; cc < 4; ++cc){
    const int c = (cg << 2) + cc;
    const size_t idx = (((size_t)((b << 6) + c)) << 12) + i0b + il;
    const float o = Of[0][il][c] + Of[1][il][c] + Of[2][il][c] + Of[3][il][c];
    out[idx] = fmaf(gamma, o, x[idx]);
  }
}

extern "C" void kernel_launch(void* const* d_in, const int* in_sizes, int n_in,
                              void* d_out, int out_size, void* d_ws, size_t ws_size,
                              hipStream_t stream)
{
  (void)in_sizes; (void)n_in; (void)out_size; (void)ws_size;
  const float* x   = (const float*)d_in[0];
  const float* Wf  = (const float*)d_in[1];
  const float* bfv = (const float*)d_in[2];
  const float* Wg  = (const float*)d_in[3];
  const float* bgv = (const float*)d_in[4];
  const float* Wh  = (const float*)d_in[5];
  const float* bhv = (const float*)d_in[6];
  const float* gm  = (const float*)d_in[7];
  float* out = (float*)d_out;

  // workspace: Qg 512K | Kf 512K | V 4M | Lsp 128K  (= 5.125 MB)
  char* ws = (char*)d_ws;
  u16*  Qg = (u16*)(ws);
  u16*  Kf = (u16*)(ws + (1u << 19));
  u16*  Vv = (u16*)(ws + (1u << 20));
  unsigned* Lsp = (unsigned*)(ws + (1u << 20) + (1u << 22));

  prep_kernel<<<512, 512, 0, stream>>>(x, Wf, bfv, Wg, bgv, Wh, bhv, Qg, Kf, Vv);
  pass1_kernel<<<1024, 256, 0, stream>>>(Qg, Kf, Lsp);
  pass2_kernel<<<1024, 512, 0, stream>>>(Qg, Kf, Vv, Lsp, x, gm, out);
}

// Round 16
// 88.707 us; speedup vs baseline: 2.4635x; 1.2997x over previous
//
#include <hip/hip_runtime.h>

#define NN 4096   // W*H
#define LOG2E 1.4426950408889634f
// layouts in d_ws:
//   Qg  [B][N][8] bf16 : g-projection (row i), natural order
//   Kf  [B][N][8] bf16 : f-projection * log2e (row j), natural order  (r11-verified)
//   V   [B][N/32][C][32] bf16 : h-projection, j-TILED (4KB tile = [64 c][32 slots]);
//                        within each tile, actual column jl stored at slot
//                        q(jl) = jl<16 ? 8*(jl>>2)+(jl&3) : 8*((jl-16)>>2)+4+((jl-16)&3)
//                        (r15-verified permutation -> zero-shuffle P-pack)
//   Lsp [B][N] u32     : packed {bf16 hi, bf16 lo} of -log2(z_j), natural order

typedef unsigned short u16;
typedef __attribute__((ext_vector_type(8))) short bf16x8;
typedef __attribute__((ext_vector_type(4))) float f32x4;

__device__ __forceinline__ u16 f2bf(float f){
  union { float f; unsigned u; } v; v.f = f;
  unsigned r = v.u + 0x7fffu + ((v.u >> 16) & 1u);   // RNE
  return (u16)(r >> 16);
}
__device__ __forceinline__ float bf2f(u16 h){
  union { unsigned u; float f; } v; v.u = ((unsigned)h) << 16;
  return v.f;
}

// ---------------- prep: 1x1 convs ---------------- (r15-verified; ONLY the V store
// macro-address changes: flat [C][N] -> tiled [N/32][C][32], same within-32 slot q(jl))
__global__ __launch_bounds__(512, 4) void prep_kernel(
    const float* __restrict__ x,
    const float* __restrict__ Wf, const float* __restrict__ bfv,
    const float* __restrict__ Wg, const float* __restrict__ bgv,
    const float* __restrict__ Wh, const float* __restrict__ bhv,
    u16* __restrict__ Qg, u16* __restrict__ Kf, u16* __restrict__ V)
{
  __shared__ float xl[64][68];   // [pixel][channel]
  const int tid = threadIdx.x;
  const int lane = tid & 63, q8 = tid >> 6;   // q8 in [0,8), wave-uniform
  const int b = blockIdx.x >> 6;
  const int i0 = (blockIdx.x & 63) << 6;
  const float* xb = x + ((size_t)b << 18);

  for (int r = 0; r < 8; ++r){
    int c = (r << 3) + q8;
    xl[lane][c] = xb[((size_t)c << 12) + i0 + lane];
  }
  __syncthreads();

  float xr[64];
#pragma unroll
  for (int c4 = 0; c4 < 16; ++c4){
    f32x4 v = *(const f32x4*)&xl[lane][c4 << 2];
    xr[c4*4+0]=v[0]; xr[c4*4+1]=v[1]; xr[c4*4+2]=v[2]; xr[c4*4+3]=v[3];
  }

  // h-projection: 8 channels per thread; store at tile (i>>5), row co, slot q(jl)
  const int i = i0 + lane;
  const int jl = i & 31;
  const int qp = (jl < 16) ? (((jl >> 2) << 3) | (jl & 3))
                           : ((((jl - 16) >> 2) << 3) | (4 + ((jl - 16) & 3)));
  u16* vp = V + ((size_t)b << 18) + ((size_t)(i >> 5) << 11) + qp;
#pragma unroll
  for (int ch = 0; ch < 8; ++ch){
    int co = (q8 << 3) + ch;
    float acc = bhv[co];
    const float* wr = Wh + (co << 6);
#pragma unroll
    for (int c = 0; c < 64; ++c) acc = fmaf(wr[c], xr[c], acc);
    vp[co << 5] = f2bf(acc);
  }
  // f (scaled by log2e) and g: natural row order (r13-verified)
  {
    const int row = (b << 12) + i;
    float a0 = bfv[q8], c0 = bgv[q8];
    const float* w0 = Wf + (q8 << 6);
    const float* u0 = Wg + (q8 << 6);
#pragma unroll
    for (int c = 0; c < 64; ++c){
      float xv = xr[c];
      a0 = fmaf(w0[c], xv, a0);
      c0 = fmaf(u0[c], xv, c0);
    }
    Kf[(size_t)row * 8 + q8] = f2bf(a0 * LOG2E);
    Qg[(size_t)row * 8 + q8] = f2bf(c0);
  }
}

// ---------------- pass1 ---------------- (r13-verified, byte-identical; does not read V)
__global__ __launch_bounds__(256, 4) void pass1_kernel(
    const u16* __restrict__ Qg, const u16* __restrict__ Kf, unsigned* __restrict__ Lsp)
{
  __shared__ float zp[4][32];
  const int tid = threadIdx.x;
  const int w = tid >> 6, lane = tid & 63;
  const int l15 = lane & 15, g = lane >> 4;
  const int b = blockIdx.x >> 7;
  const int j0 = (blockIdx.x & 127) << 5;

  bf16x8 af0 = {0,0,0,0,0,0,0,0}, af1 = {0,0,0,0,0,0,0,0};
  if (lane < 16){
    af0 = *(const bf16x8*)(Kf + ((size_t)((b << 12) + j0 + lane)) * 8);
    af1 = *(const bf16x8*)(Kf + ((size_t)((b << 12) + j0 + 16 + lane)) * 8);
  }

  const u16* qb = Qg + ((size_t)(b << 12)) * 8;
  float z[8];
#pragma unroll
  for (int r = 0; r < 8; ++r) z[r] = 0.f;
  const f32x4 zero4 = {0.f,0.f,0.f,0.f};
  const int ibase = w << 10;
  for (int t = 0; t < 32; ++t){
    const int i = ibase + (t << 5);
    bf16x8 b0 = {0,0,0,0,0,0,0,0}, b1 = {0,0,0,0,0,0,0,0};
    if (lane < 16){
      b0 = *(const bf16x8*)(qb + (size_t)(i + lane) * 8);
      b1 = *(const bf16x8*)(qb + (size_t)(i + 16 + lane) * 8);
    }
    f32x4 s00 = __builtin_amdgcn_mfma_f32_16x16x32_bf16(af0, b0, zero4, 0,0,0);
    f32x4 s01 = __builtin_amdgcn_mfma_f32_16x16x32_bf16(af0, b1, zero4, 0,0,0);
    f32x4 s10 = __builtin_amdgcn_mfma_f32_16x16x32_bf16(af1, b0, zero4, 0,0,0);
    f32x4 s11 = __builtin_amdgcn_mfma_f32_16x16x32_bf16(af1, b1, zero4, 0,0,0);
#pragma unroll
    for (int r = 0; r < 4; ++r){
      z[r]     += __builtin_amdgcn_exp2f(s00[r]) + __builtin_amdgcn_exp2f(s01[r]);
      z[4 + r] += __builtin_amdgcn_exp2f(s10[r]) + __builtin_amdgcn_exp2f(s11[r]);
    }
  }
#pragma unroll
  for (int r = 0; r < 8; ++r){
#pragma unroll
    for (int off = 1; off < 16; off <<= 1)
      z[r] += __shfl_xor(z[r], off, 64);
  }
  if (l15 == 0){
#pragma unroll
    for (int r = 0; r < 4; ++r){
      zp[w][(g << 2) + r]      = z[r];
      zp[w][16 + (g << 2) + r] = z[4 + r];
    }
  }
  __syncthreads();
  if (tid < 32){
    float zs = zp[0][tid] + zp[1][tid] + zp[2][tid] + zp[3][tid];
    float nL = -__log2f(zs);
    u16 hi = f2bf(nL);
    u16 lo = f2bf(nL - bf2f(hi));
    Lsp[((size_t)b << 12) + j0 + tid] = (unsigned)hi | ((unsigned)lo << 16);
  }
}

// zero-shuffle P pack (r15-verified): lane g's own QK outputs, in register order,
// ARE B-slots 8g..8g+7 (V's permuted slot storage makes A[c,k]=V[c,j0+jmap(k)])
__device__ __forceinline__ bf16x8 pack_pb(const f32x4 sl, const f32x4 sh){
  union { unsigned d[4]; bf16x8 v; } u;
  u.d[0] = (unsigned)f2bf(__builtin_amdgcn_exp2f(sl[0])) | ((unsigned)f2bf(__builtin_amdgcn_exp2f(sl[1])) << 16);
  u.d[1] = (unsigned)f2bf(__builtin_amdgcn_exp2f(sl[2])) | ((unsigned)f2bf(__builtin_amdgcn_exp2f(sl[3])) << 16);
  u.d[2] = (unsigned)f2bf(__builtin_amdgcn_exp2f(sh[0])) | ((unsigned)f2bf(__builtin_amdgcn_exp2f(sh[1])) << 16);
  u.d[3] = (unsigned)f2bf(__builtin_amdgcn_exp2f(sh[2])) | ((unsigned)f2bf(__builtin_amdgcn_exp2f(sh[3])) << 16);
  return u.v;
}

// ---------------- pass2 ---------------- (r15-verified geometry & datapath; ONLY change:
// vf loads read the j-tiled V -- each vf is a fully-coalesced contiguous 1KB)
__global__ __launch_bounds__(512, 4) void pass2_kernel(
    const u16* __restrict__ Qg, const u16* __restrict__ Kf,
    const u16* __restrict__ V, const unsigned* __restrict__ Lsp,
    const float* __restrict__ x, const float* __restrict__ gammap,
    float* __restrict__ out)
{
  __shared__ __align__(16) float Of[4][32][68];   // 34.8 KB, epilogue only
  const int tid = threadIdx.x;
  const int w = tid >> 6, lane = tid & 63;        // w = j-eighth
  const int l15 = lane & 15, g = lane >> 4;
  const int bid = blockIdx.x;
  const int b = bid & 7;                          // per-batch XCD chunking (1024 % 8 == 0)
  const int i0b = (bid >> 3) << 5;                // 32-row i-tile

  const u16* kb = Kf + ((size_t)(b << 12)) * 8;
  const u16* vb = V + ((size_t)b << 18);
  const unsigned* Lb = Lsp + ((size_t)b << 12);

  bf16x8 qf0 = {0,0,0,0,0,0,0,0}, qf1 = {0,0,0,0,0,0,0,0};
  if (lane < 16){
    qf0 = *(const bf16x8*)(Qg + ((size_t)((b << 12) + i0b + lane)) * 8);
    qf1 = *(const bf16x8*)(Qg + ((size_t)((b << 12) + i0b + 16 + lane)) * 8);
  } else if (lane < 32){
    ((unsigned*)&qf0)[0] = 0x3F803F80u;   // k=8,9 partners = 1.0,1.0
    ((unsigned*)&qf1)[0] = 0x3F803F80u;
  }

  f32x4 acc[2][4];
#pragma unroll
  for (int s = 0; s < 2; ++s)
#pragma unroll
    for (int ct = 0; ct < 4; ++ct) acc[s][ct] = (f32x4){0.f,0.f,0.f,0.f};

  const f32x4 zero4 = {0.f,0.f,0.f,0.f};
  const int jbase = w << 9;                        // 512-j range per wave

  auto load_k = [&](int j0, bf16x8& kk0, bf16x8& kk1){
    kk0 = (bf16x8){0,0,0,0,0,0,0,0}; kk1 = (bf16x8){0,0,0,0,0,0,0,0};
    if (lane < 16){
      kk0 = *(const bf16x8*)(kb + (size_t)(j0 + lane) * 8);
      kk1 = *(const bf16x8*)(kb + (size_t)(j0 + 16 + lane) * 8);
    } else if (lane < 32){
      ((unsigned*)&kk0)[0] = Lb[j0 + l15];        // k=8,9: {-Lg_hi, -Lg_lo}
      ((unsigned*)&kk1)[0] = Lb[j0 + 16 + l15];
    }
  };

  bf16x8 kc0, kc1;
  load_k(jbase, kc0, kc1);                        // K/L(0)

  // per-lane V offset inside a 4KB tile: lane (g,l15) -> bytes l15*64 + g*16
  const u16* vlane = vb + (l15 << 5) + (g << 3);

  for (int t = 0; t < 16; ++t){
    const int j0 = jbase + (t << 5);
    // prefetch K/L(t+1): non-blocking issue, consumed next iteration
    bf16x8 kn0 = {0,0,0,0,0,0,0,0}, kn1 = {0,0,0,0,0,0,0,0};
    if (t < 15) load_k(j0 + 32, kn0, kn1);
    // V fragments: 4 x contiguous 1KB from the j0-tile ([64 c][32 slots] = 4KB)
    const u16* vt = vlane + ((size_t)(j0 >> 5) << 11);
    bf16x8 vf0 = *(const bf16x8*)(vt);
    bf16x8 vf1 = *(const bf16x8*)(vt + (16 << 5));
    bf16x8 vf2 = *(const bf16x8*)(vt + (32 << 5));
    bf16x8 vf3 = *(const bf16x8*)(vt + (48 << 5));
    // swapped QK^T with -log2(z) folded in (kc ready since last iteration)
    f32x4 sl0 = __builtin_amdgcn_mfma_f32_16x16x32_bf16(kc0, qf0, zero4, 0,0,0);
    f32x4 sh0 = __builtin_amdgcn_mfma_f32_16x16x32_bf16(kc1, qf0, zero4, 0,0,0);
    f32x4 sl1 = __builtin_amdgcn_mfma_f32_16x16x32_bf16(kc0, qf1, zero4, 0,0,0);
    f32x4 sh1 = __builtin_amdgcn_mfma_f32_16x16x32_bf16(kc1, qf1, zero4, 0,0,0);
    bf16x8 pb0 = pack_pb(sl0, sh0);
    bf16x8 pb1 = pack_pb(sl1, sh1);
    // PV: O[c,i] += V x P
    __builtin_amdgcn_s_setprio(1);
    acc[0][0] = __builtin_amdgcn_mfma_f32_16x16x32_bf16(vf0, pb0, acc[0][0], 0,0,0);
    acc[0][1] = __builtin_amdgcn_mfma_f32_16x16x32_bf16(vf1, pb0, acc[0][1], 0,0,0);
    acc[0][2] = __builtin_amdgcn_mfma_f32_16x16x32_bf16(vf2, pb0, acc[0][2], 0,0,0);
    acc[0][3] = __builtin_amdgcn_mfma_f32_16x16x32_bf16(vf3, pb0, acc[0][3], 0,0,0);
    acc[1][0] = __builtin_amdgcn_mfma_f32_16x16x32_bf16(vf0, pb1, acc[1][0], 0,0,0);
    acc[1][1] = __builtin_amdgcn_mfma_f32_16x16x32_bf16(vf1, pb1, acc[1][1], 0,0,0);
    acc[1][2] = __builtin_amdgcn_mfma_f32_16x16x32_bf16(vf2, pb1, acc[1][2], 0,0,0);
    acc[1][3] = __builtin_amdgcn_mfma_f32_16x16x32_bf16(vf3, pb1, acc[1][3], 0,0,0);
    __builtin_amdgcn_s_setprio(0);
    kc0 = kn0; kc1 = kn1;
  }

  // epilogue (r14/r15-verified, unchanged): tree combine of 8 j-partials
  if (w < 4){
#pragma unroll
    for (int s = 0; s < 2; ++s)
#pragma unroll
      for (int ct = 0; ct < 4; ++ct)
        *(f32x4*)&Of[w][(s << 4) + l15][(ct << 4) + (g << 2)] = acc[s][ct];
  }
  __syncthreads();
  if (w >= 4){
#pragma unroll
    for (int s = 0; s < 2; ++s)
#pragma unroll
      for (int ct = 0; ct < 4; ++ct){
        f32x4* p = (f32x4*)&Of[w - 4][(s << 4) + l15][(ct << 4) + (g << 2)];
        *p += acc[s][ct];
      }
  }
  __syncthreads();
  const float gamma = gammap[0];
  const int il = tid & 31, cg = tid >> 5;   // cg in [0,16)
#pragma unroll
  for (int cc = 0; cc < 4; ++cc){
    const int c = (cg << 2) + cc;
    const size_t idx = (((size_t)((b << 6) + c)) << 12) + i0b + il;
    const float o = Of[0][il][c] + Of[1][il][c] + Of[2][il][c] + Of[3][il][c];
    out[idx] = fmaf(gamma, o, x[idx]);
  }
}

extern "C" void kernel_launch(void* const* d_in, const int* in_sizes, int n_in,
                              void* d_out, int out_size, void* d_ws, size_t ws_size,
                              hipStream_t stream)
{
  (void)in_sizes; (void)n_in; (void)out_size; (void)ws_size;
  const float* x   = (const float*)d_in[0];
  const float* Wf  = (const float*)d_in[1];
  const float* bfv = (const float*)d_in[2];
  const float* Wg  = (const float*)d_in[3];
  const float* bgv = (const float*)d_in[4];
  const float* Wh  = (const float*)d_in[5];
  const float* bhv = (const float*)d_in[6];
  const float* gm  = (const float*)d_in[7];
  float* out = (float*)d_out;

  // workspace: Qg 512K | Kf 512K | V 4M | Lsp 128K  (= 5.125 MB)
  char* ws = (char*)d_ws;
  u16*  Qg = (u16*)(ws);
  u16*  Kf = (u16*)(ws + (1u << 19));
  u16*  Vv = (u16*)(ws + (1u << 20));
  unsigned* Lsp = (unsigned*)(ws + (1u << 20) + (1u << 22));

  prep_kernel<<<512, 512, 0, stream>>>(x, Wf, bfv, Wg, bgv, Wh, bhv, Qg, Kf, Vv);
  pass1_kernel<<<1024, 256, 0, stream>>>(Qg, Kf, Lsp);
  pass2_kernel<<<1024, 512, 0, stream>>>(Qg, Kf, Vv, Lsp, x, gm, out);
}

// Round 17
// 86.223 us; speedup vs baseline: 2.5344x; 1.0288x over previous
//
#include <hip/hip_runtime.h>

#define NN 4096   // W*H
#define LOG2E 1.4426950408889634f
// layouts in d_ws:
//   Qg  [B][N][8] bf16 : g-projection (row i), natural order
//   Kf  [B][N][8] bf16 : f-projection * log2e (row j), natural order  (r11-verified)
//   V   [B][N/32][C][32] bf16 : h-projection, j-TILED (4KB tile = [64 c][32 slots]);
//                        within each tile, actual column jl stored at slot
//                        q(jl) = jl<16 ? 8*(jl>>2)+(jl&3) : 8*((jl-16)>>2)+4+((jl-16)&3)
//                        (r15/r16-verified -> zero-shuffle P-pack, dense 1KB vf loads)
//   Lsp [B][N] u32     : packed {bf16 hi, bf16 lo} of -log2(z_j), natural order

typedef unsigned short u16;
typedef __attribute__((ext_vector_type(8))) short bf16x8;
typedef __attribute__((ext_vector_type(4))) float f32x4;
typedef __attribute__((ext_vector_type(2))) __bf16 bfv2;

__device__ __forceinline__ u16 f2bf(float f){
  union { float f; unsigned u; } v; v.f = f;
  unsigned r = v.u + 0x7fffu + ((v.u >> 16) & 1u);   // RNE
  return (u16)(r >> 16);
}
__device__ __forceinline__ float bf2f(u16 h){
  union { unsigned u; float f; } v; v.u = ((unsigned)h) << 16;
  return v.f;
}
// native packed convert: compiler lowers paired __bf16 casts to v_cvt_pk_bf16_f32 on gfx950
__device__ __forceinline__ unsigned pk2(float a, float b){
  bfv2 t; t[0] = (__bf16)a; t[1] = (__bf16)b;
  return __builtin_bit_cast(unsigned, t);
}

// ---------------- prep: 1x1 convs ---------------- (r16-verified, byte-identical)
__global__ __launch_bounds__(512, 4) void prep_kernel(
    const float* __restrict__ x,
    const float* __restrict__ Wf, const float* __restrict__ bfv,
    const float* __restrict__ Wg, const float* __restrict__ bgv,
    const float* __restrict__ Wh, const float* __restrict__ bhv,
    u16* __restrict__ Qg, u16* __restrict__ Kf, u16* __restrict__ V)
{
  __shared__ float xl[64][68];   // [pixel][channel]
  const int tid = threadIdx.x;
  const int lane = tid & 63, q8 = tid >> 6;   // q8 in [0,8), wave-uniform
  const int b = blockIdx.x >> 6;
  const int i0 = (blockIdx.x & 63) << 6;
  const float* xb = x + ((size_t)b << 18);

  for (int r = 0; r < 8; ++r){
    int c = (r << 3) + q8;
    xl[lane][c] = xb[((size_t)c << 12) + i0 + lane];
  }
  __syncthreads();

  float xr[64];
#pragma unroll
  for (int c4 = 0; c4 < 16; ++c4){
    f32x4 v = *(const f32x4*)&xl[lane][c4 << 2];
    xr[c4*4+0]=v[0]; xr[c4*4+1]=v[1]; xr[c4*4+2]=v[2]; xr[c4*4+3]=v[3];
  }

  // h-projection: 8 channels per thread; store at tile (i>>5), row co, slot q(jl)
  const int i = i0 + lane;
  const int jl = i & 31;
  const int qp = (jl < 16) ? (((jl >> 2) << 3) | (jl & 3))
                           : ((((jl - 16) >> 2) << 3) | (4 + ((jl - 16) & 3)));
  u16* vp = V + ((size_t)b << 18) + ((size_t)(i >> 5) << 11) + qp;
#pragma unroll
  for (int ch = 0; ch < 8; ++ch){
    int co = (q8 << 3) + ch;
    float acc = bhv[co];
    const float* wr = Wh + (co << 6);
#pragma unroll
    for (int c = 0; c < 64; ++c) acc = fmaf(wr[c], xr[c], acc);
    vp[co << 5] = f2bf(acc);
  }
  // f (scaled by log2e) and g: natural row order
  {
    const int row = (b << 12) + i;
    float a0 = bfv[q8], c0 = bgv[q8];
    const float* w0 = Wf + (q8 << 6);
    const float* u0 = Wg + (q8 << 6);
#pragma unroll
    for (int c = 0; c < 64; ++c){
      float xv = xr[c];
      a0 = fmaf(w0[c], xv, a0);
      c0 = fmaf(u0[c], xv, c0);
    }
    Kf[(size_t)row * 8 + q8] = f2bf(a0 * LOG2E);
    Qg[(size_t)row * 8 + q8] = f2bf(c0);
  }
}

// ---------------- pass1: Lsp_j = split(-log2 z_j) ----------------
// r13 datapath; concurrency doubled: 8 waves/block (8-way i-split, 16 iters each)
// -> 1024 blocks x 8 waves = 32 waves/CU (was grid-capped at 16).
__global__ __launch_bounds__(512, 4) void pass1_kernel(
    const u16* __restrict__ Qg, const u16* __restrict__ Kf, unsigned* __restrict__ Lsp)
{
  __shared__ float zp[8][32];
  const int tid = threadIdx.x;
  const int w = tid >> 6, lane = tid & 63;
  const int l15 = lane & 15, g = lane >> 4;
  const int b = blockIdx.x >> 7;
  const int j0 = (blockIdx.x & 127) << 5;

  bf16x8 af0 = {0,0,0,0,0,0,0,0}, af1 = {0,0,0,0,0,0,0,0};
  if (lane < 16){
    af0 = *(const bf16x8*)(Kf + ((size_t)((b << 12) + j0 + lane)) * 8);
    af1 = *(const bf16x8*)(Kf + ((size_t)((b << 12) + j0 + 16 + lane)) * 8);
  }

  const u16* qb = Qg + ((size_t)(b << 12)) * 8;
  float z[8];
#pragma unroll
  for (int r = 0; r < 8; ++r) z[r] = 0.f;
  const f32x4 zero4 = {0.f,0.f,0.f,0.f};
  const int ibase = w << 9;                      // 512-i range per wave
  for (int t = 0; t < 16; ++t){
    const int i = ibase + (t << 5);
    bf16x8 b0 = {0,0,0,0,0,0,0,0}, b1 = {0,0,0,0,0,0,0,0};
    if (lane < 16){
      b0 = *(const bf16x8*)(qb + (size_t)(i + lane) * 8);
      b1 = *(const bf16x8*)(qb + (size_t)(i + 16 + lane) * 8);
    }
    f32x4 s00 = __builtin_amdgcn_mfma_f32_16x16x32_bf16(af0, b0, zero4, 0,0,0);
    f32x4 s01 = __builtin_amdgcn_mfma_f32_16x16x32_bf16(af0, b1, zero4, 0,0,0);
    f32x4 s10 = __builtin_amdgcn_mfma_f32_16x16x32_bf16(af1, b0, zero4, 0,0,0);
    f32x4 s11 = __builtin_amdgcn_mfma_f32_16x16x32_bf16(af1, b1, zero4, 0,0,0);
#pragma unroll
    for (int r = 0; r < 4; ++r){
      z[r]     += __builtin_amdgcn_exp2f(s00[r]) + __builtin_amdgcn_exp2f(s01[r]);
      z[4 + r] += __builtin_amdgcn_exp2f(s10[r]) + __builtin_amdgcn_exp2f(s11[r]);
    }
  }
#pragma unroll
  for (int r = 0; r < 8; ++r){
#pragma unroll
    for (int off = 1; off < 16; off <<= 1)
      z[r] += __shfl_xor(z[r], off, 64);
  }
  if (l15 == 0){
#pragma unroll
    for (int r = 0; r < 4; ++r){
      zp[w][(g << 2) + r]      = z[r];
      zp[w][16 + (g << 2) + r] = z[4 + r];
    }
  }
  __syncthreads();
  if (tid < 32){
    float zs = (zp[0][tid] + zp[1][tid]) + (zp[2][tid] + zp[3][tid])
             + (zp[4][tid] + zp[5][tid]) + (zp[6][tid] + zp[7][tid]);
    float nL = -__log2f(zs);
    u16 hi = f2bf(nL);
    u16 lo = f2bf(nL - bf2f(hi));
    Lsp[((size_t)b << 12) + j0 + tid] = (unsigned)hi | ((unsigned)lo << 16);
  }
}

// zero-shuffle P pack (r15/r16-verified layout); converts now via native
// v_cvt_pk_bf16_f32 (compiler-lowered __bf16 casts) instead of manual RNE bit-ops
__device__ __forceinline__ bf16x8 pack_pb(const f32x4 sl, const f32x4 sh){
  union { unsigned d[4]; bf16x8 v; } u;
  u.d[0] = pk2(__builtin_amdgcn_exp2f(sl[0]), __builtin_amdgcn_exp2f(sl[1]));
  u.d[1] = pk2(__builtin_amdgcn_exp2f(sl[2]), __builtin_amdgcn_exp2f(sl[3]));
  u.d[2] = pk2(__builtin_amdgcn_exp2f(sh[0]), __builtin_amdgcn_exp2f(sh[1]));
  u.d[3] = pk2(__builtin_amdgcn_exp2f(sh[2]), __builtin_amdgcn_exp2f(sh[3]));
  return u.v;
}

// ---------------- pass2 ---------------- (r16-verified geometry & datapath; ONLY change:
// pack_pb converts use native cvt_pk instead of 16 manual f2bf + 8 packs)
__global__ __launch_bounds__(512, 4) void pass2_kernel(
    const u16* __restrict__ Qg, const u16* __restrict__ Kf,
    const u16* __restrict__ V, const unsigned* __restrict__ Lsp,
    const float* __restrict__ x, const float* __restrict__ gammap,
    float* __restrict__ out)
{
  __shared__ __align__(16) float Of[4][32][68];   // 34.8 KB, epilogue only
  const int tid = threadIdx.x;
  const int w = tid >> 6, lane = tid & 63;        // w = j-eighth
  const int l15 = lane & 15, g = lane >> 4;
  const int bid = blockIdx.x;
  const int b = bid & 7;                          // per-batch XCD chunking (1024 % 8 == 0)
  const int i0b = (bid >> 3) << 5;                // 32-row i-tile

  const u16* kb = Kf + ((size_t)(b << 12)) * 8;
  const u16* vb = V + ((size_t)b << 18);
  const unsigned* Lb = Lsp + ((size_t)b << 12);

  bf16x8 qf0 = {0,0,0,0,0,0,0,0}, qf1 = {0,0,0,0,0,0,0,0};
  if (lane < 16){
    qf0 = *(const bf16x8*)(Qg + ((size_t)((b << 12) + i0b + lane)) * 8);
    qf1 = *(const bf16x8*)(Qg + ((size_t)((b << 12) + i0b + 16 + lane)) * 8);
  } else if (lane < 32){
    ((unsigned*)&qf0)[0] = 0x3F803F80u;   // k=8,9 partners = 1.0,1.0
    ((unsigned*)&qf1)[0] = 0x3F803F80u;
  }

  f32x4 acc[2][4];
#pragma unroll
  for (int s = 0; s < 2; ++s)
#pragma unroll
    for (int ct = 0; ct < 4; ++ct) acc[s][ct] = (f32x4){0.f,0.f,0.f,0.f};

  const f32x4 zero4 = {0.f,0.f,0.f,0.f};
  const int jbase = w << 9;                        // 512-j range per wave

  auto load_k = [&](int j0, bf16x8& kk0, bf16x8& kk1){
    kk0 = (bf16x8){0,0,0,0,0,0,0,0}; kk1 = (bf16x8){0,0,0,0,0,0,0,0};
    if (lane < 16){
      kk0 = *(const bf16x8*)(kb + (size_t)(j0 + lane) * 8);
      kk1 = *(const bf16x8*)(kb + (size_t)(j0 + 16 + lane) * 8);
    } else if (lane < 32){
      ((unsigned*)&kk0)[0] = Lb[j0 + l15];        // k=8,9: {-Lg_hi, -Lg_lo}
      ((unsigned*)&kk1)[0] = Lb[j0 + 16 + l15];
    }
  };

  bf16x8 kc0, kc1;
  load_k(jbase, kc0, kc1);                        // K/L(0)

  // per-lane V offset inside a 4KB tile: lane (g,l15) -> bytes l15*64 + g*16
  const u16* vlane = vb + (l15 << 5) + (g << 3);

  for (int t = 0; t < 16; ++t){
    const int j0 = jbase + (t << 5);
    // prefetch K/L(t+1): non-blocking issue, consumed next iteration
    bf16x8 kn0 = {0,0,0,0,0,0,0,0}, kn1 = {0,0,0,0,0,0,0,0};
    if (t < 15) load_k(j0 + 32, kn0, kn1);
    // V fragments: 4 x contiguous 1KB from the j0-tile ([64 c][32 slots] = 4KB)
    const u16* vt = vlane + ((size_t)(j0 >> 5) << 11);
    bf16x8 vf0 = *(const bf16x8*)(vt);
    bf16x8 vf1 = *(const bf16x8*)(vt + (16 << 5));
    bf16x8 vf2 = *(const bf16x8*)(vt + (32 << 5));
    bf16x8 vf3 = *(const bf16x8*)(vt + (48 << 5));
    // swapped QK^T with -log2(z) folded in (kc ready since last iteration)
    f32x4 sl0 = __builtin_amdgcn_mfma_f32_16x16x32_bf16(kc0, qf0, zero4, 0,0,0);
    f32x4 sh0 = __builtin_amdgcn_mfma_f32_16x16x32_bf16(kc1, qf0, zero4, 0,0,0);
    f32x4 sl1 = __builtin_amdgcn_mfma_f32_16x16x32_bf16(kc0, qf1, zero4, 0,0,0);
    f32x4 sh1 = __builtin_amdgcn_mfma_f32_16x16x32_bf16(kc1, qf1, zero4, 0,0,0);
    bf16x8 pb0 = pack_pb(sl0, sh0);
    bf16x8 pb1 = pack_pb(sl1, sh1);
    // PV: O[c,i] += V x P
    __builtin_amdgcn_s_setprio(1);
    acc[0][0] = __builtin_amdgcn_mfma_f32_16x16x32_bf16(vf0, pb0, acc[0][0], 0,0,0);
    acc[0][1] = __builtin_amdgcn_mfma_f32_16x16x32_bf16(vf1, pb0, acc[0][1], 0,0,0);
    acc[0][2] = __builtin_amdgcn_mfma_f32_16x16x32_bf16(vf2, pb0, acc[0][2], 0,0,0);
    acc[0][3] = __builtin_amdgcn_mfma_f32_16x16x32_bf16(vf3, pb0, acc[0][3], 0,0,0);
    acc[1][0] = __builtin_amdgcn_mfma_f32_16x16x32_bf16(vf0, pb1, acc[1][0], 0,0,0);
    acc[1][1] = __builtin_amdgcn_mfma_f32_16x16x32_bf16(vf1, pb1, acc[1][1], 0,0,0);
    acc[1][2] = __builtin_amdgcn_mfma_f32_16x16x32_bf16(vf2, pb1, acc[1][2], 0,0,0);
    acc[1][3] = __builtin_amdgcn_mfma_f32_16x16x32_bf16(vf3, pb1, acc[1][3], 0,0,0);
    __builtin_amdgcn_s_setprio(0);
    kc0 = kn0; kc1 = kn1;
  }

  // epilogue (r14/r15/r16-verified, unchanged): tree combine of 8 j-partials
  if (w < 4){
#pragma unroll
    for (int s = 0; s < 2; ++s)
#pragma unroll
      for (int ct = 0; ct < 4; ++ct)
        *(f32x4*)&Of[w][(s << 4) + l15][(ct << 4) + (g << 2)] = acc[s][ct];
  }
  __syncthreads();
  if (w >= 4){
#pragma unroll
    for (int s = 0; s < 2; ++s)
#pragma unroll
      for (int ct = 0; ct < 4; ++ct){
        f32x4* p = (f32x4*)&Of[w - 4][(s << 4) + l15][(ct << 4) + (g << 2)];
        *p += acc[s][ct];
      }
  }
  __syncthreads();
  const float gamma = gammap[0];
  const int il = tid & 31, cg = tid >> 5;   // cg in [0,16)
#pragma unroll
  for (int cc = 0; cc < 4; ++cc){
    const int c = (cg << 2) + cc;
    const size_t idx = (((size_t)((b << 6) + c)) << 12) + i0b + il;
    const float o = Of[0][il][c] + Of[1][il][c] + Of[2][il][c] + Of[3][il][c];
    out[idx] = fmaf(gamma, o, x[idx]);
  }
}

extern "C" void kernel_launch(void* const* d_in, const int* in_sizes, int n_in,
                              void* d_out, int out_size, void* d_ws, size_t ws_size,
                              hipStream_t stream)
{
  (void)in_sizes; (void)n_in; (void)out_size; (void)ws_size;
  const float* x   = (const float*)d_in[0];
  const float* Wf  = (const float*)d_in[1];
  const float* bfv = (const float*)d_in[2];
  const float* Wg  = (const float*)d_in[3];
  const float* bgv = (const float*)d_in[4];
  const float* Wh  = (const float*)d_in[5];
  const float* bhv = (const float*)d_in[6];
  const float* gm  = (const float*)d_in[7];
  float* out = (float*)d_out;

  // workspace: Qg 512K | Kf 512K | V 4M | Lsp 128K  (= 5.125 MB)
  char* ws = (char*)d_ws;
  u16*  Qg = (u16*)(ws);
  u16*  Kf = (u16*)(ws + (1u << 19));
  u16*  Vv = (u16*)(ws + (1u << 20));
  unsigned* Lsp = (unsigned*)(ws + (1u << 20) + (1u << 22));

  prep_kernel<<<512, 512, 0, stream>>>(x, Wf, bfv, Wg, bgv, Wh, bhv, Qg, Kf, Vv);
  pass1_kernel<<<1024, 512, 0, stream>>>(Qg, Kf, Lsp);
  pass2_kernel<<<1024, 512, 0, stream>>>(Qg, Kf, Vv, Lsp, x, gm, out);
}

// Round 18
// 71.846 us; speedup vs baseline: 3.0416x; 1.2001x over previous
//
#include <hip/hip_runtime.h>

#define NN 4096   // W*H
#define LOG2E 1.4426950408889634f
// layouts in d_ws:
//   Qg  [B][N][8] bf16 : g-projection (row i), natural order
//   Kf  [B][N][8] bf16 : f-projection * log2e (row j), natural order
//   V   [B][N/32][2][64][16] bf16 : h-projection, j-tiled for 32x32 MFMA A-frags:
//        tile (j>>5), j-half jh=(j>>4)&1, c, slot s(j16)=8*((j16>>2)&1)+(j16&3)+4*(j16>>3)
//        -> each PV A-fragment is a contiguous 1KB full-wave load, zero shuffles
//   Lsp [B][N] u32     : packed {bf16 hi, bf16 lo} of -log2(z_j), natural order

typedef unsigned short u16;
typedef __attribute__((ext_vector_type(8))) short bf16x8;
typedef __attribute__((ext_vector_type(4))) float f32x4;
typedef __attribute__((ext_vector_type(16))) float f32x16;
typedef __attribute__((ext_vector_type(2))) __bf16 bfv2;

__device__ __forceinline__ u16 f2bf(float f){
  union { float f; unsigned u; } v; v.f = f;
  unsigned r = v.u + 0x7fffu + ((v.u >> 16) & 1u);   // RNE
  return (u16)(r >> 16);
}
__device__ __forceinline__ float bf2f(u16 h){
  union { unsigned u; float f; } v; v.u = ((unsigned)h) << 16;
  return v.f;
}
__device__ __forceinline__ unsigned pk2(float a, float b){
  bfv2 t; t[0] = (__bf16)a; t[1] = (__bf16)b;
  return __builtin_bit_cast(unsigned, t);
}

// ---------------- prep: 1x1 convs ---------------- (r16/r17-verified; ONLY the V-store
// addressing changes to the [tile][jh][c][slot] layout)
__global__ __launch_bounds__(512, 4) void prep_kernel(
    const float* __restrict__ x,
    const float* __restrict__ Wf, const float* __restrict__ bfv,
    const float* __restrict__ Wg, const float* __restrict__ bgv,
    const float* __restrict__ Wh, const float* __restrict__ bhv,
    u16* __restrict__ Qg, u16* __restrict__ Kf, u16* __restrict__ V)
{
  __shared__ float xl[64][68];   // [pixel][channel]
  const int tid = threadIdx.x;
  const int lane = tid & 63, q8 = tid >> 6;   // q8 in [0,8), wave-uniform
  const int b = blockIdx.x >> 6;
  const int i0 = (blockIdx.x & 63) << 6;
  const float* xb = x + ((size_t)b << 18);

  for (int r = 0; r < 8; ++r){
    int c = (r << 3) + q8;
    xl[lane][c] = xb[((size_t)c << 12) + i0 + lane];
  }
  __syncthreads();

  float xr[64];
#pragma unroll
  for (int c4 = 0; c4 < 16; ++c4){
    f32x4 v = *(const f32x4*)&xl[lane][c4 << 2];
    xr[c4*4+0]=v[0]; xr[c4*4+1]=v[1]; xr[c4*4+2]=v[2]; xr[c4*4+3]=v[3];
  }

  // h-projection: 8 channels per thread -> V[tile][jh][c][slot]
  const int i = i0 + lane;
  const int jh = (i >> 4) & 1;
  const int j16 = i & 15;
  const int sl = (((j16 >> 2) & 1) << 3) + (j16 & 3) + ((j16 >> 3) << 2);
  u16* vp = V + ((size_t)b << 18) + ((size_t)(i >> 5) << 11) + (jh << 10) + sl;
#pragma unroll
  for (int ch = 0; ch < 8; ++ch){
    int co = (q8 << 3) + ch;
    float acc = bhv[co];
    const float* wr = Wh + (co << 6);
#pragma unroll
    for (int c = 0; c < 64; ++c) acc = fmaf(wr[c], xr[c], acc);
    vp[co << 4] = f2bf(acc);
  }
  // f (scaled by log2e) and g: natural row order
  {
    const int row = (b << 12) + i;
    float a0 = bfv[q8], c0 = bgv[q8];
    const float* w0 = Wf + (q8 << 6);
    const float* u0 = Wg + (q8 << 6);
#pragma unroll
    for (int c = 0; c < 64; ++c){
      float xv = xr[c];
      a0 = fmaf(w0[c], xv, a0);
      c0 = fmaf(u0[c], xv, c0);
    }
    Kf[(size_t)row * 8 + q8] = f2bf(a0 * LOG2E);
    Qg[(size_t)row * 8 + q8] = f2bf(c0);
  }
}

// ---------------- pass1 ---------------- (r17-verified, byte-identical; does not read V)
__global__ __launch_bounds__(512, 4) void pass1_kernel(
    const u16* __restrict__ Qg, const u16* __restrict__ Kf, unsigned* __restrict__ Lsp)
{
  __shared__ float zp[8][32];
  const int tid = threadIdx.x;
  const int w = tid >> 6, lane = tid & 63;
  const int l15 = lane & 15, g = lane >> 4;
  const int b = blockIdx.x >> 7;
  const int j0 = (blockIdx.x & 127) << 5;

  bf16x8 af0 = {0,0,0,0,0,0,0,0}, af1 = {0,0,0,0,0,0,0,0};
  if (lane < 16){
    af0 = *(const bf16x8*)(Kf + ((size_t)((b << 12) + j0 + lane)) * 8);
    af1 = *(const bf16x8*)(Kf + ((size_t)((b << 12) + j0 + 16 + lane)) * 8);
  }

  const u16* qb = Qg + ((size_t)(b << 12)) * 8;
  float z[8];
#pragma unroll
  for (int r = 0; r < 8; ++r) z[r] = 0.f;
  const f32x4 zero4 = {0.f,0.f,0.f,0.f};
  const int ibase = w << 9;                      // 512-i range per wave
  for (int t = 0; t < 16; ++t){
    const int i = ibase + (t << 5);
    bf16x8 b0 = {0,0,0,0,0,0,0,0}, b1 = {0,0,0,0,0,0,0,0};
    if (lane < 16){
      b0 = *(const bf16x8*)(qb + (size_t)(i + lane) * 8);
      b1 = *(const bf16x8*)(qb + (size_t)(i + 16 + lane) * 8);
    }
    f32x4 s00 = __builtin_amdgcn_mfma_f32_16x16x32_bf16(af0, b0, zero4, 0,0,0);
    f32x4 s01 = __builtin_amdgcn_mfma_f32_16x16x32_bf16(af0, b1, zero4, 0,0,0);
    f32x4 s10 = __builtin_amdgcn_mfma_f32_16x16x32_bf16(af1, b0, zero4, 0,0,0);
    f32x4 s11 = __builtin_amdgcn_mfma_f32_16x16x32_bf16(af1, b1, zero4, 0,0,0);
#pragma unroll
    for (int r = 0; r < 4; ++r){
      z[r]     += __builtin_amdgcn_exp2f(s00[r]) + __builtin_amdgcn_exp2f(s01[r]);
      z[4 + r] += __builtin_amdgcn_exp2f(s10[r]) + __builtin_amdgcn_exp2f(s11[r]);
    }
  }
#pragma unroll
  for (int r = 0; r < 8; ++r){
#pragma unroll
    for (int off = 1; off < 16; off <<= 1)
      z[r] += __shfl_xor(z[r], off, 64);
  }
  if (l15 == 0){
#pragma unroll
    for (int r = 0; r < 4; ++r){
      zp[w][(g << 2) + r]      = z[r];
      zp[w][16 + (g << 2) + r] = z[4 + r];
    }
  }
  __syncthreads();
  if (tid < 32){
    float zs = (zp[0][tid] + zp[1][tid]) + (zp[2][tid] + zp[3][tid])
             + (zp[4][tid] + zp[5][tid]) + (zp[6][tid] + zp[7][tid]);
    float nL = -__log2f(zs);
    u16 hi = f2bf(nL);
    u16 lo = f2bf(nL - bf2f(hi));
    Lsp[((size_t)b << 12) + j0 + tid] = (unsigned)hi | ((unsigned)lo << 16);
  }
}

// pack 8 consecutive QK-output regs (in order) into a PV B-fragment:
// 32x32 D row = (r&3)+8*(r>>2)+4*g2 matches B slot j-map by construction (V slot layout)
__device__ __forceinline__ bf16x8 pack8(const f32x16 s, const int base){
  union { unsigned d[4]; bf16x8 v; } u;
  u.d[0] = pk2(__builtin_amdgcn_exp2f(s[base+0]), __builtin_amdgcn_exp2f(s[base+1]));
  u.d[1] = pk2(__builtin_amdgcn_exp2f(s[base+2]), __builtin_amdgcn_exp2f(s[base+3]));
  u.d[2] = pk2(__builtin_amdgcn_exp2f(s[base+4]), __builtin_amdgcn_exp2f(s[base+5]));
  u.d[3] = pk2(__builtin_amdgcn_exp2f(s[base+6]), __builtin_amdgcn_exp2f(s[base+7]));
  return u.v;
}

// ---------------- pass2: O[c,i] = sum_j 2^{S2[j,i]-log2 z_j} * V[c,j]; out = gamma*O + x --------
// 32x32x16 MFMA version: block = 64 i-rows x 8 j-eighth waves (512 blocks x 512 thr).
// Per 32-j iter: 1 K/L A-frag (full-wave masked), 4 contiguous-1KB V A-frags,
// 2 QK MFMA (L folded at k=8,9), in-order register P-pack, 8 PV MFMA.
// V traffic per wave amortized over 64 i-rows (2x r17).
__global__ __launch_bounds__(512, 4) void pass2_kernel(
    const u16* __restrict__ Qg, const u16* __restrict__ Kf,
    const u16* __restrict__ V, const unsigned* __restrict__ Lsp,
    const float* __restrict__ x, const float* __restrict__ gammap,
    float* __restrict__ out)
{
  __shared__ __align__(16) float Of[4][32][68];   // 34.8 KB, epilogue only
  const int tid = threadIdx.x;
  const int w = tid >> 6, lane = tid & 63;        // w = j-eighth
  const int l31 = lane & 31, g2 = lane >> 5;
  const int bid = blockIdx.x;
  const int b = bid & 7;                          // per-batch XCD chunking (512 % 8 == 0)
  const int i0b = (bid >> 3) << 6;                // 64-row i-tile

  const u16* kb = Kf + ((size_t)(b << 12)) * 8;
  const u16* vb = V + ((size_t)b << 18);
  const unsigned* Lb = Lsp + ((size_t)b << 12);

  // Q B-frags for i-blocks 0,1: lane (l31,g2): B[k=8g2+e][col=l31]
  bf16x8 qB0 = {0,0,0,0,0,0,0,0}, qB1 = {0,0,0,0,0,0,0,0};
  if (lane < 32){
    qB0 = *(const bf16x8*)(Qg + ((size_t)((b << 12) + i0b + l31)) * 8);
    qB1 = *(const bf16x8*)(Qg + ((size_t)((b << 12) + i0b + 32 + l31)) * 8);
  } else {
    ((unsigned*)&qB0)[0] = 0x3F803F80u;   // k=8,9 partners = 1.0,1.0
    ((unsigned*)&qB1)[0] = 0x3F803F80u;
  }

  f32x16 acc[2][2];   // [cb][ib]
#pragma unroll
  for (int cb = 0; cb < 2; ++cb)
#pragma unroll
    for (int ib = 0; ib < 2; ++ib)
#pragma unroll
      for (int r = 0; r < 16; ++r) acc[cb][ib][r] = 0.f;

  f32x16 zero16;
#pragma unroll
  for (int r = 0; r < 16; ++r) zero16[r] = 0.f;

  const int jbase = w << 9;                        // 512-j range per wave
  // per-lane V offset inside a [2][64][16] tile (2KB u16 units): c=l31(+32cb), slot 8g2
  const u16* vlane = vb + (l31 << 4) + (g2 << 3);

  for (int t = 0; t < 16; ++t){
    const int j0 = jbase + (t << 5);
    // K/L A-frag: lanes 0-31 = Kf rows (k0-7), lanes 32-63 = {-L pair, 0...} (k8-15)
    bf16x8 ka = {0,0,0,0,0,0,0,0};
    if (lane < 32) ka = *(const bf16x8*)(kb + (size_t)(j0 + l31) * 8);
    else ((unsigned*)&ka)[0] = Lb[j0 + l31];
    // V A-frags: 4 x contiguous 1KB from tile [2 jh][64 c][16 slots]
    const u16* vt = vlane + ((size_t)(j0 >> 5) << 11);
    bf16x8 vf00 = *(const bf16x8*)(vt);            // cb0 jh0
    bf16x8 vf10 = *(const bf16x8*)(vt + 512);      // cb1 jh0
    bf16x8 vf01 = *(const bf16x8*)(vt + 1024);     // cb0 jh1
    bf16x8 vf11 = *(const bf16x8*)(vt + 1536);     // cb1 jh1
    // swapped QK^T (32x32x16), -log2 z folded at k=8,9
    f32x16 s0 = __builtin_amdgcn_mfma_f32_32x32x16_bf16(ka, qB0, zero16, 0,0,0);
    f32x16 s1 = __builtin_amdgcn_mfma_f32_32x32x16_bf16(ka, qB1, zero16, 0,0,0);
    // in-order P pack: regs 0-7 -> j-half 0, regs 8-15 -> j-half 1
    bf16x8 p00 = pack8(s0, 0), p01 = pack8(s0, 8);
    bf16x8 p10 = pack8(s1, 0), p11 = pack8(s1, 8);
    // PV: acc[cb][ib] += V[cb][jh] x P[ib][jh]
    __builtin_amdgcn_s_setprio(1);
    acc[0][0] = __builtin_amdgcn_mfma_f32_32x32x16_bf16(vf00, p00, acc[0][0], 0,0,0);
    acc[0][0] = __builtin_amdgcn_mfma_f32_32x32x16_bf16(vf01, p01, acc[0][0], 0,0,0);
    acc[1][0] = __builtin_amdgcn_mfma_f32_32x32x16_bf16(vf10, p00, acc[1][0], 0,0,0);
    acc[1][0] = __builtin_amdgcn_mfma_f32_32x32x16_bf16(vf11, p01, acc[1][0], 0,0,0);
    acc[0][1] = __builtin_amdgcn_mfma_f32_32x32x16_bf16(vf00, p10, acc[0][1], 0,0,0);
    acc[0][1] = __builtin_amdgcn_mfma_f32_32x32x16_bf16(vf01, p11, acc[0][1], 0,0,0);
    acc[1][1] = __builtin_amdgcn_mfma_f32_32x32x16_bf16(vf10, p10, acc[1][1], 0,0,0);
    acc[1][1] = __builtin_amdgcn_mfma_f32_32x32x16_bf16(vf11, p11, acc[1][1], 0,0,0);
    __builtin_amdgcn_s_setprio(0);
  }

  // epilogue: acc[cb][ib] reg r -> O[c = 32cb + (r&3)+8*(r>>2)+4*g2][i = i0b+32ib+l31]
  // two ib-passes through Of[4][i 32][c 68]; tree combine of 8 j-partials each
  const float gamma = gammap[0];
#pragma unroll
  for (int ib = 0; ib < 2; ++ib){
    if (ib) __syncthreads();          // guard Of reuse between passes
    if (w < 4){
#pragma unroll
      for (int cb = 0; cb < 2; ++cb)
#pragma unroll
        for (int rq = 0; rq < 4; ++rq){
          f32x4 q = { acc[cb][ib][4*rq+0], acc[cb][ib][4*rq+1],
                      acc[cb][ib][4*rq+2], acc[cb][ib][4*rq+3] };
          *(f32x4*)&Of[w][l31][(cb << 5) + (rq << 3) + (g2 << 2)] = q;
        }
    }
    __syncthreads();
    if (w >= 4){
#pragma unroll
      for (int cb = 0; cb < 2; ++cb)
#pragma unroll
        for (int rq = 0; rq < 4; ++rq){
          f32x4 q = { acc[cb][ib][4*rq+0], acc[cb][ib][4*rq+1],
                      acc[cb][ib][4*rq+2], acc[cb][ib][4*rq+3] };
          f32x4* p = (f32x4*)&Of[w - 4][l31][(cb << 5) + (rq << 3) + (g2 << 2)];
          *p += q;
        }
    }
    __syncthreads();
    const int il = tid & 31, cg = tid >> 5;   // cg in [0,16)
#pragma unroll
    for (int cc = 0; cc < 4; ++cc){
      const int c = (cg << 2) + cc;
      const size_t idx = (((size_t)((b << 6) + c)) << 12) + i0b + (ib << 5) + il;
      const float o = Of[0][il][c] + Of[1][il][c] + Of[2][il][c] + Of[3][il][c];
      out[idx] = fmaf(gamma, o, x[idx]);
    }
  }
}

extern "C" void kernel_launch(void* const* d_in, const int* in_sizes, int n_in,
                              void* d_out, int out_size, void* d_ws, size_t ws_size,
                              hipStream_t stream)
{
  (void)in_sizes; (void)n_in; (void)out_size; (void)ws_size;
  const float* x   = (const float*)d_in[0];
  const float* Wf  = (const float*)d_in[1];
  const float* bfv = (const float*)d_in[2];
  const float* Wg  = (const float*)d_in[3];
  const float* bgv = (const float*)d_in[4];
  const float* Wh  = (const float*)d_in[5];
  const float* bhv = (const float*)d_in[6];
  const float* gm  = (const float*)d_in[7];
  float* out = (float*)d_out;

  // workspace: Qg 512K | Kf 512K | V 4M | Lsp 128K  (= 5.125 MB)
  char* ws = (char*)d_ws;
  u16*  Qg = (u16*)(ws);
  u16*  Kf = (u16*)(ws + (1u << 19));
  u16*  Vv = (u16*)(ws + (1u << 20));
  unsigned* Lsp = (unsigned*)(ws + (1u << 20) + (1u << 22));

  prep_kernel<<<512, 512, 0, stream>>>(x, Wf, bfv, Wg, bgv, Wh, bhv, Qg, Kf, Vv);
  pass1_kernel<<<1024, 512, 0, stream>>>(Qg, Kf, Lsp);
  pass2_kernel<<<512, 512, 0, stream>>>(Qg, Kf, Vv, Lsp, x, gm, out);
}

// Round 19
// 67.977 us; speedup vs baseline: 3.2148x; 1.0569x over previous
//
#include <hip/hip_runtime.h>

#define NN 4096   // W*H
#define LOG2E 1.4426950408889634f
// layouts in d_ws:
//   Qg  [B][N][8] bf16 : g-projection (row i), natural order
//   Kf  [B][N][8] bf16 : f-projection * log2e (row j), natural order
//   V   [B][N/32][2][64][16] bf16 : h-projection, j-tiled for 32x32 MFMA A-frags
//        (r18-verified): tile (j>>5), jh=(j>>4)&1, c, slot s(j16)=8*((j16>>2)&1)+(j16&3)+4*(j16>>3)
//   Lsp [B][N] u32     : packed {bf16 hi, bf16 lo} of -log2(z_j), natural order

typedef unsigned short u16;
typedef __attribute__((ext_vector_type(8))) short bf16x8;
typedef __attribute__((ext_vector_type(4))) float f32x4;
typedef __attribute__((ext_vector_type(16))) float f32x16;
typedef __attribute__((ext_vector_type(2))) __bf16 bfv2;

__device__ __forceinline__ u16 f2bf(float f){
  union { float f; unsigned u; } v; v.f = f;
  unsigned r = v.u + 0x7fffu + ((v.u >> 16) & 1u);   // RNE
  return (u16)(r >> 16);
}
__device__ __forceinline__ float bf2f(u16 h){
  union { unsigned u; float f; } v; v.u = ((unsigned)h) << 16;
  return v.f;
}
__device__ __forceinline__ unsigned pk2(float a, float b){
  bfv2 t; t[0] = (__bf16)a; t[1] = (__bf16)b;
  return __builtin_bit_cast(unsigned, t);
}

// ---------------- prep: 1x1 convs ---------------- (r18-verified, byte-identical)
__global__ __launch_bounds__(512, 4) void prep_kernel(
    const float* __restrict__ x,
    const float* __restrict__ Wf, const float* __restrict__ bfv,
    const float* __restrict__ Wg, const float* __restrict__ bgv,
    const float* __restrict__ Wh, const float* __restrict__ bhv,
    u16* __restrict__ Qg, u16* __restrict__ Kf, u16* __restrict__ V)
{
  __shared__ float xl[64][68];   // [pixel][channel]
  const int tid = threadIdx.x;
  const int lane = tid & 63, q8 = tid >> 6;   // q8 in [0,8), wave-uniform
  const int b = blockIdx.x >> 6;
  const int i0 = (blockIdx.x & 63) << 6;
  const float* xb = x + ((size_t)b << 18);

  for (int r = 0; r < 8; ++r){
    int c = (r << 3) + q8;
    xl[lane][c] = xb[((size_t)c << 12) + i0 + lane];
  }
  __syncthreads();

  float xr[64];
#pragma unroll
  for (int c4 = 0; c4 < 16; ++c4){
    f32x4 v = *(const f32x4*)&xl[lane][c4 << 2];
    xr[c4*4+0]=v[0]; xr[c4*4+1]=v[1]; xr[c4*4+2]=v[2]; xr[c4*4+3]=v[3];
  }

  // h-projection: 8 channels per thread -> V[tile][jh][c][slot]
  const int i = i0 + lane;
  const int jh = (i >> 4) & 1;
  const int j16 = i & 15;
  const int sl = (((j16 >> 2) & 1) << 3) + (j16 & 3) + ((j16 >> 3) << 2);
  u16* vp = V + ((size_t)b << 18) + ((size_t)(i >> 5) << 11) + (jh << 10) + sl;
#pragma unroll
  for (int ch = 0; ch < 8; ++ch){
    int co = (q8 << 3) + ch;
    float acc = bhv[co];
    const float* wr = Wh + (co << 6);
#pragma unroll
    for (int c = 0; c < 64; ++c) acc = fmaf(wr[c], xr[c], acc);
    vp[co << 4] = f2bf(acc);
  }
  // f (scaled by log2e) and g: natural row order
  {
    const int row = (b << 12) + i;
    float a0 = bfv[q8], c0 = bgv[q8];
    const float* w0 = Wf + (q8 << 6);
    const float* u0 = Wg + (q8 << 6);
#pragma unroll
    for (int c = 0; c < 64; ++c){
      float xv = xr[c];
      a0 = fmaf(w0[c], xv, a0);
      c0 = fmaf(u0[c], xv, c0);
    }
    Kf[(size_t)row * 8 + q8] = f2bf(a0 * LOG2E);
    Qg[(size_t)row * 8 + q8] = f2bf(c0);
  }
}

// ---------------- pass1: Lsp_j = split(-log2 z_j), z_j = sum_i 2^{S2[j,i]} ----------------
// 32x32x16 version (r18-verified QK pattern, no L-fold): 64-row j-tile per block,
// 2 A-frags share each full-32-lane Q B-frag load; 8 waves split i 8-way (16 iters).
// Wave-iters halved vs r17 (131k -> 65k), VMEM instrs per element quartered.
__global__ __launch_bounds__(512, 4) void pass1_kernel(
    const u16* __restrict__ Qg, const u16* __restrict__ Kf, unsigned* __restrict__ Lsp)
{
  __shared__ float zp[8][64];   // 2 KB
  const int tid = threadIdx.x;
  const int w = tid >> 6, lane = tid & 63;
  const int l31 = lane & 31, g2 = lane >> 5;
  const int bid = blockIdx.x;
  const int b = bid & 7;                       // XCD chunking: same-XCD blocks share Qg[b]
  const int j0 = ((bid >> 3) & 63) << 6;       // 64-row j-tile

  // A-frags: lanes 0-31 = Kf rows (k0-7); lanes 32-63 = zero (k8-15)
  bf16x8 ka0 = {0,0,0,0,0,0,0,0}, ka1 = {0,0,0,0,0,0,0,0};
  if (lane < 32){
    ka0 = *(const bf16x8*)(Kf + ((size_t)((b << 12) + j0 + l31)) * 8);
    ka1 = *(const bf16x8*)(Kf + ((size_t)((b << 12) + j0 + 32 + l31)) * 8);
  }

  const u16* qb = Qg + ((size_t)(b << 12)) * 8;
  f32x16 z0, z1;
#pragma unroll
  for (int r = 0; r < 16; ++r){ z0[r] = 0.f; z1[r] = 0.f; }
  f32x16 zero16;
#pragma unroll
  for (int r = 0; r < 16; ++r) zero16[r] = 0.f;

  const int ibase = w << 9;                    // 512-i range per wave
  for (int t = 0; t < 16; ++t){
    const int i = ibase + (t << 5);
    bf16x8 qf = {0,0,0,0,0,0,0,0};
    if (lane < 32) qf = *(const bf16x8*)(qb + (size_t)(i + l31) * 8);
    f32x16 s0 = __builtin_amdgcn_mfma_f32_32x32x16_bf16(ka0, qf, zero16, 0,0,0);
    f32x16 s1 = __builtin_amdgcn_mfma_f32_32x32x16_bf16(ka1, qf, zero16, 0,0,0);
#pragma unroll
    for (int r = 0; r < 16; ++r){
      z0[r] += __builtin_amdgcn_exp2f(s0[r]);
      z1[r] += __builtin_amdgcn_exp2f(s1[r]);
    }
  }
  // reduce over the 32 i-columns (lanes l31) within each g2 half
#pragma unroll
  for (int r = 0; r < 16; ++r){
#pragma unroll
    for (int off = 1; off < 32; off <<= 1){
      z0[r] += __shfl_xor(z0[r], off, 64);
      z1[r] += __shfl_xor(z1[r], off, 64);
    }
  }
  if (l31 == 0){
#pragma unroll
    for (int r = 0; r < 16; ++r){
      const int jl = (r & 3) + ((r >> 2) << 3) + (g2 << 2);   // D row mapping (m74/m101)
      zp[w][jl]      = z0[r];
      zp[w][32 + jl] = z1[r];
    }
  }
  __syncthreads();
  if (tid < 64){
    float zs = (zp[0][tid] + zp[1][tid]) + (zp[2][tid] + zp[3][tid])
             + (zp[4][tid] + zp[5][tid]) + (zp[6][tid] + zp[7][tid]);
    float nL = -__log2f(zs);
    u16 hi = f2bf(nL);
    u16 lo = f2bf(nL - bf2f(hi));
    Lsp[((size_t)b << 12) + j0 + tid] = (unsigned)hi | ((unsigned)lo << 16);
  }
}

// pack 8 consecutive QK-output regs into a PV B-fragment (r18-verified)
__device__ __forceinline__ bf16x8 pack8(const f32x16 s, const int base){
  union { unsigned d[4]; bf16x8 v; } u;
  u.d[0] = pk2(__builtin_amdgcn_exp2f(s[base+0]), __builtin_amdgcn_exp2f(s[base+1]));
  u.d[1] = pk2(__builtin_amdgcn_exp2f(s[base+2]), __builtin_amdgcn_exp2f(s[base+3]));
  u.d[2] = pk2(__builtin_amdgcn_exp2f(s[base+4]), __builtin_amdgcn_exp2f(s[base+5]));
  u.d[3] = pk2(__builtin_amdgcn_exp2f(s[base+6]), __builtin_amdgcn_exp2f(s[base+7]));
  return u.v;
}

// ---------------- pass2 ---------------- (r18-verified datapath; changes: 4-wave blocks
// (j-quarters, 32 iters) and a LOAD-ONLY unroll-2 pipeline -- loads of t+1 issue before
// PV(t), so PV waits a counted vmcnt instead of a full drain (T14). Compute order
// identical to r18. __launch_bounds__(256,2) gives the ~170-reg live set headroom.)
__global__ __launch_bounds__(256, 2) void pass2_kernel(
    const u16* __restrict__ Qg, const u16* __restrict__ Kf,
    const u16* __restrict__ V, const unsigned* __restrict__ Lsp,
    const float* __restrict__ x, const float* __restrict__ gammap,
    float* __restrict__ out)
{
  __shared__ __align__(16) float Of[2][64][68];   // 34.8 KB, epilogue only
  const int tid = threadIdx.x;
  const int w = tid >> 6, lane = tid & 63;        // w = j-quarter
  const int l31 = lane & 31, g2 = lane >> 5;
  const int bid = blockIdx.x;
  const int b = bid & 7;                          // per-batch XCD chunking (512 % 8 == 0)
  const int i0b = (bid >> 3) << 6;                // 64-row i-tile

  const u16* kb = Kf + ((size_t)(b << 12)) * 8;
  const u16* vb = V + ((size_t)b << 18);
  const unsigned* Lb = Lsp + ((size_t)b << 12);

  bf16x8 qB0 = {0,0,0,0,0,0,0,0}, qB1 = {0,0,0,0,0,0,0,0};
  if (lane < 32){
    qB0 = *(const bf16x8*)(Qg + ((size_t)((b << 12) + i0b + l31)) * 8);
    qB1 = *(const bf16x8*)(Qg + ((size_t)((b << 12) + i0b + 32 + l31)) * 8);
  } else {
    ((unsigned*)&qB0)[0] = 0x3F803F80u;   // k=8,9 partners = 1.0,1.0
    ((unsigned*)&qB1)[0] = 0x3F803F80u;
  }

  f32x16 acc00, acc01, acc10, acc11;   // [cb][ib]
#pragma unroll
  for (int r = 0; r < 16; ++r){ acc00[r]=0.f; acc01[r]=0.f; acc10[r]=0.f; acc11[r]=0.f; }
  f32x16 zero16;
#pragma unroll
  for (int r = 0; r < 16; ++r) zero16[r] = 0.f;

  const int jbase = w << 10;                       // 1024-j range per wave, 32 iters
  const u16* vlane = vb + (l31 << 4) + (g2 << 3);

  auto load_all = [&](int tt, bf16x8& ka, bf16x8& v00, bf16x8& v10, bf16x8& v01, bf16x8& v11){
    const int j0 = jbase + (tt << 5);
    ka = (bf16x8){0,0,0,0,0,0,0,0};
    if (lane < 32) ka = *(const bf16x8*)(kb + (size_t)(j0 + l31) * 8);
    else ((unsigned*)&ka)[0] = Lb[j0 + l31];       // k=8,9: {-Lg_hi, -Lg_lo}
    const u16* vt = vlane + ((size_t)(j0 >> 5) << 11);
    v00 = *(const bf16x8*)(vt);                    // cb0 jh0
    v10 = *(const bf16x8*)(vt + 512);              // cb1 jh0
    v01 = *(const bf16x8*)(vt + 1024);             // cb0 jh1
    v11 = *(const bf16x8*)(vt + 1536);             // cb1 jh1
  };

#define COMPUTE(KA, V00, V10, V01, V11)                                              \
  {                                                                                  \
    f32x16 s0 = __builtin_amdgcn_mfma_f32_32x32x16_bf16(KA, qB0, zero16, 0,0,0);     \
    f32x16 s1 = __builtin_amdgcn_mfma_f32_32x32x16_bf16(KA, qB1, zero16, 0,0,0);     \
    bf16x8 p00 = pack8(s0, 0), p01 = pack8(s0, 8);                                   \
    bf16x8 p10 = pack8(s1, 0), p11 = pack8(s1, 8);                                   \
    __builtin_amdgcn_s_setprio(1);                                                   \
    acc00 = __builtin_amdgcn_mfma_f32_32x32x16_bf16(V00, p00, acc00, 0,0,0);         \
    acc00 = __builtin_amdgcn_mfma_f32_32x32x16_bf16(V01, p01, acc00, 0,0,0);         \
    acc10 = __builtin_amdgcn_mfma_f32_32x32x16_bf16(V10, p00, acc10, 0,0,0);         \
    acc10 = __builtin_amdgcn_mfma_f32_32x32x16_bf16(V11, p01, acc10, 0,0,0);         \
    acc01 = __builtin_amdgcn_mfma_f32_32x32x16_bf16(V00, p10, acc01, 0,0,0);         \
    acc01 = __builtin_amdgcn_mfma_f32_32x32x16_bf16(V01, p11, acc01, 0,0,0);         \
    acc11 = __builtin_amdgcn_mfma_f32_32x32x16_bf16(V10, p10, acc11, 0,0,0);         \
    acc11 = __builtin_amdgcn_mfma_f32_32x32x16_bf16(V11, p11, acc11, 0,0,0);         \
    __builtin_amdgcn_s_setprio(0);                                                   \
  }

  bf16x8 kaA, a00, a10, a01, a11;
  bf16x8 kaB, b00, b10, b01, b11;
  load_all(0, kaA, a00, a10, a01, a11);

  for (int t = 0; t < 32; t += 2){
    load_all(t + 1, kaB, b00, b10, b01, b11);       // issue-early: covers PV(A)'s wait
    COMPUTE(kaA, a00, a10, a01, a11);
    if (t + 2 < 32) load_all(t + 2, kaA, a00, a10, a01, a11);
    COMPUTE(kaB, b00, b10, b01, b11);
  }
#undef COMPUTE

  // epilogue: acc[cb][ib] reg r -> O[c = 32cb + (r&3)+8*(r>>2)+4*g2][i = i0b+32ib+l31]
  // waves 0,1 write Of[w]; waves 2,3 add into Of[w-2]; final sum of 2 partials.
  const float gamma = gammap[0];
#pragma unroll
  for (int pass = 0; pass < 2; ++pass){
    // pass 0: waves 0,1 store; pass 1: waves 2,3 accumulate
    if ((w >> 1) == pass){
      const int slot = w & 1;
#pragma unroll
      for (int cb = 0; cb < 2; ++cb)
#pragma unroll
        for (int ib = 0; ib < 2; ++ib){
          const f32x16& a = cb ? (ib ? acc11 : acc10) : (ib ? acc01 : acc00);
#pragma unroll
          for (int rq = 0; rq < 4; ++rq){
            f32x4 q = { a[4*rq+0], a[4*rq+1], a[4*rq+2], a[4*rq+3] };
            f32x4* p = (f32x4*)&Of[slot][(ib << 5) + l31][(cb << 5) + (rq << 3) + (g2 << 2)];
            if (pass == 0) *p = q; else *p += q;
          }
        }
    }
    __syncthreads();
  }
  const int il = tid & 63, cg = tid >> 6;   // cg in [0,4)
#pragma unroll
  for (int cc = 0; cc < 16; ++cc){
    const int c = (cg << 4) + cc;
    const size_t idx = (((size_t)((b << 6) + c)) << 12) + i0b + il;
    const float o = Of[0][il][c] + Of[1][il][c];
    out[idx] = fmaf(gamma, o, x[idx]);
  }
}

extern "C" void kernel_launch(void* const* d_in, const int* in_sizes, int n_in,
                              void* d_out, int out_size, void* d_ws, size_t ws_size,
                              hipStream_t stream)
{
  (void)in_sizes; (void)n_in; (void)out_size; (void)ws_size;
  const float* x   = (const float*)d_in[0];
  const float* Wf  = (const float*)d_in[1];
  const float* bfv = (const float*)d_in[2];
  const float* Wg  = (const float*)d_in[3];
  const float* bgv = (const float*)d_in[4];
  const float* Wh  = (const float*)d_in[5];
  const float* bhv = (const float*)d_in[6];
  const float* gm  = (const float*)d_in[7];
  float* out = (float*)d_out;

  // workspace: Qg 512K | Kf 512K | V 4M | Lsp 128K  (= 5.125 MB)
  char* ws = (char*)d_ws;
  u16*  Qg = (u16*)(ws);
  u16*  Kf = (u16*)(ws + (1u << 19));
  u16*  Vv = (u16*)(ws + (1u << 20));
  unsigned* Lsp = (unsigned*)(ws + (1u << 20) + (1u << 22));

  prep_kernel<<<512, 512, 0, stream>>>(x, Wf, bfv, Wg, bgv, Wh, bhv, Qg, Kf, Vv);
  pass1_kernel<<<512, 512, 0, stream>>>(Qg, Kf, Lsp);
  pass2_kernel<<<512, 256, 0, stream>>>(Qg, Kf, Vv, Lsp, x, gm, out);
}